// Round 1
// baseline (1097.299 us; speedup 1.0000x reference)
//
#include <hip/hip_runtime.h>

#define B_  64
#define T_  256
#define H_  512
#define NH_ 8
#define DH_ 64
#define M_  16384

typedef float  f32x4 __attribute__((ext_vector_type(4)));
typedef __bf16 b16x8 __attribute__((ext_vector_type(8)));
typedef __bf16 b16x4 __attribute__((ext_vector_type(4)));

// ---------------- fp32 -> bf16 convert ----------------
__global__ __launch_bounds__(256) void cvt_f32_bf16_k(const float* __restrict__ in,
                                                      __bf16* __restrict__ out) {
  size_t i = ((size_t)blockIdx.x * 256 + threadIdx.x) * 4;
  f32x4 v = *(const f32x4*)(in + i);
  b16x4 o;
  o[0] = (__bf16)v[0]; o[1] = (__bf16)v[1]; o[2] = (__bf16)v[2]; o[3] = (__bf16)v[3];
  *(b16x4*)(out + i) = o;
}

// ---------------- weight transpose + convert: out[c][r] = in[r][c] ----------------
__global__ __launch_bounds__(256) void transpose_cvt(const float* __restrict__ in,
                                                     __bf16* __restrict__ out, int R, int C) {
  __shared__ float tile[32][33];
  size_t zoff = (size_t)blockIdx.z * R * C;
  in += zoff; out += zoff;
  int c0 = blockIdx.x * 32, r0 = blockIdx.y * 32;
  int tx = threadIdx.x & 31, ty = threadIdx.x >> 5;
  for (int yy = ty; yy < 32; yy += 8)
    tile[yy][tx] = in[(size_t)(r0 + yy) * C + c0 + tx];
  __syncthreads();
  for (int yy = ty; yy < 32; yy += 8)
    out[(size_t)(c0 + yy) * R + r0 + tx] = (__bf16)tile[tx][yy];
}

// ---------------- emotion K/V: (7,512) = emo @ W + b ----------------
__global__ __launch_bounds__(512) void emo_kv(const float* __restrict__ emo,
                                              const float* __restrict__ Wk, const float* __restrict__ bk,
                                              const float* __restrict__ Wv, const float* __restrict__ bv,
                                              float* __restrict__ kout, float* __restrict__ vout) {
  int e = blockIdx.x, n = threadIdx.x;
  const float* W = blockIdx.y ? Wv : Wk;
  const float* bb = blockIdx.y ? bv : bk;
  float* o = blockIdx.y ? vout : kout;
  float acc = 0.f;
  for (int kk = 0; kk < 512; ++kk) acc += emo[e * 512 + kk] * W[kk * 512 + n];
  o[e * 512 + n] = acc + bb[n];
}

// ---------------- MFMA GEMM: C[M,N] = A[M,K](bf16) @ Bt[N,K]^T + bias ----------------
template<bool OB, bool HB>
__global__ __launch_bounds__(256) void gemm_bt(const __bf16* __restrict__ A,
                                               const __bf16* __restrict__ Bt,
                                               const float* __restrict__ bias,
                                               void* __restrict__ Cv,
                                               int N, int K, int lda, int ldc) {
  __shared__ __attribute__((aligned(16))) __bf16 As[128][40];
  __shared__ __attribute__((aligned(16))) __bf16 Bs[128][40];
  const int tid = threadIdx.x, lane = tid & 63, wid = tid >> 6;
  const int wm = wid & 1, wn = wid >> 1;
  const int m0 = blockIdx.y * 128, n0 = blockIdx.x * 128;
  const int l15 = lane & 15, l16 = lane >> 4;
  f32x4 acc[4][4] = {};
  for (int k0 = 0; k0 < K; k0 += 32) {
#pragma unroll
    for (int j = 0; j < 2; ++j) {
      int c = tid + j * 256;
      int row = c >> 2, ko = (c & 3) * 8;
      *(b16x8*)&As[row][ko] = *(const b16x8*)(A + (size_t)(m0 + row) * lda + k0 + ko);
      *(b16x8*)&Bs[row][ko] = *(const b16x8*)(Bt + (size_t)(n0 + row) * K + k0 + ko);
    }
    __syncthreads();
    b16x8 af[4], bf[4];
#pragma unroll
    for (int m = 0; m < 4; ++m) af[m] = *(const b16x8*)&As[wm * 64 + m * 16 + l15][l16 * 8];
#pragma unroll
    for (int n = 0; n < 4; ++n) bf[n] = *(const b16x8*)&Bs[wn * 64 + n * 16 + l15][l16 * 8];
#pragma unroll
    for (int m = 0; m < 4; ++m)
#pragma unroll
      for (int n = 0; n < 4; ++n)
        acc[m][n] = __builtin_amdgcn_mfma_f32_16x16x32_bf16(af[m], bf[n], acc[m][n], 0, 0, 0);
    __syncthreads();
  }
  const int rbase = m0 + wm * 64 + l16 * 4;
  const int cb = n0 + wn * 64 + l15;
#pragma unroll
  for (int n = 0; n < 4; ++n) {
    int gc = cb + n * 16;
    float bv = HB ? bias[gc] : 0.0f;
#pragma unroll
    for (int m = 0; m < 4; ++m) {
#pragma unroll
      for (int rr = 0; rr < 4; ++rr) {
        int gr = rbase + m * 16 + rr;
        float val = acc[m][n][rr] + bv;
        if (OB) ((__bf16*)Cv)[(size_t)gr * ldc + gc] = (__bf16)val;
        else    ((float*)Cv)[(size_t)gr * ldc + gc] = val;
      }
    }
  }
}

// ---------------- sentiment attention: 7 emotion keys, 1 wave per token ----------------
__global__ __launch_bounds__(64) void sent_attn(const __bf16* __restrict__ qs,
                                                const float* __restrict__ kemo,
                                                const float* __restrict__ vemo,
                                                __bf16* __restrict__ out) {
  int m = blockIdx.x, lane = threadIdx.x;
  const __bf16* qrow = qs + (size_t)m * 512;
  for (int h = 0; h < 8; ++h) {
    float qd = (float)qrow[h * 64 + lane];
    float s[7];
#pragma unroll
    for (int e = 0; e < 7; ++e) {
      float pr = qd * kemo[e * 512 + h * 64 + lane];
#pragma unroll
      for (int off = 32; off; off >>= 1) pr += __shfl_xor(pr, off);
      s[e] = pr * 0.125f;
    }
    float mx = s[0];
#pragma unroll
    for (int e = 1; e < 7; ++e) mx = fmaxf(mx, s[e]);
    float p[7], sum = 0.f;
#pragma unroll
    for (int e = 0; e < 7; ++e) { p[e] = __expf(s[e] - mx); sum += p[e]; }
    float inv = 1.f / sum;
    float ctx = 0.f;
#pragma unroll
    for (int e = 0; e < 7; ++e) ctx += p[e] * vemo[e * 512 + h * 64 + lane];
    out[(size_t)m * 512 + h * 64 + lane] = (__bf16)(ctx * inv);
  }
}

// ---------------- fused bias-residual-LayerNorm over rows of 512 ----------------
__global__ __launch_bounds__(256) void ln_fused(const float* __restrict__ pre,
                                                const float* __restrict__ res,
                                                const float* __restrict__ g,
                                                const float* __restrict__ bt,
                                                float* __restrict__ of,
                                                __bf16* __restrict__ ob) {
  int row = blockIdx.x, t = threadIdx.x;
  size_t base = (size_t)row * 512;
  float v0 = pre[base + t] + res[base + t];
  float v1 = pre[base + 256 + t] + res[base + 256 + t];
  float s = v0 + v1, q = v0 * v0 + v1 * v1;
#pragma unroll
  for (int off = 32; off; off >>= 1) { s += __shfl_xor(s, off); q += __shfl_xor(q, off); }
  __shared__ float ls[4], lq[4];
  int wid = t >> 6, lane = t & 63;
  if (lane == 0) { ls[wid] = s; lq[wid] = q; }
  __syncthreads();
  s = ls[0] + ls[1] + ls[2] + ls[3];
  q = lq[0] + lq[1] + lq[2] + lq[3];
  float mean = s * (1.f / 512.f);
  float var = q * (1.f / 512.f) - mean * mean;
  float rstd = rsqrtf(fmaxf(var, 0.f) + 1e-12f);
  float o0 = (v0 - mean) * rstd * g[t] + bt[t];
  float o1 = (v1 - mean) * rstd * g[256 + t] + bt[256 + t];
  if (of) { of[base + t] = o0; of[base + 256 + t] = o1; }
  if (ob) { ob[base + t] = (__bf16)o0; ob[base + 256 + t] = (__bf16)o1; }
}

// ---------------- V transpose: vt[b][h][d][t] = v[(b,t)][h*64+d] ----------------
__global__ __launch_bounds__(256) void transpose_v_k(const __bf16* __restrict__ v,
                                                     __bf16* __restrict__ vt) {
  __shared__ __attribute__((aligned(16))) __bf16 tile[256][72];
  int b = blockIdx.x, h = blockIdx.y;
#pragma unroll
  for (int j = 0; j < 8; ++j) {
    int c = threadIdx.x + j * 256; int t = c >> 3, d0 = (c & 7) * 8;
    *(b16x8*)&tile[t][d0] = *(const b16x8*)(v + (size_t)(b * T_ + t) * H_ + h * DH_ + d0);
  }
  __syncthreads();
#pragma unroll
  for (int j = 0; j < 8; ++j) {
    int c = threadIdx.x + j * 256; int d = c >> 5, t0 = (c & 31) * 8;
    b16x8 o;
#pragma unroll
    for (int u = 0; u < 8; ++u) o[u] = tile[t0 + u][d];
    *(b16x8*)(vt + (size_t)(b * NH_ + h) * (DH_ * T_) + d * T_ + t0) = o;
  }
}

// ---------------- fused masked attention, one branch; 32 q-rows per block ----------------
template<int BR>
__global__ __launch_bounds__(256) void attn_branch(const __bf16* __restrict__ q,
                                                   const __bf16* __restrict__ kk_,
                                                   const __bf16* __restrict__ vt,
                                                   __bf16* __restrict__ ctx,
                                                   const int* __restrict__ lengths,
                                                   const int* __restrict__ speakers) {
  __shared__ __attribute__((aligned(16))) __bf16 Qs[32][72];
  __shared__ __attribute__((aligned(16))) __bf16 Ks[64][72];
  __shared__ __attribute__((aligned(16))) float  Ss[32][264];
  __shared__ __attribute__((aligned(16))) __bf16 Pb[32][264];
  __shared__ int spk[256];
  const int tid = threadIdx.x, lane = tid & 63, wid = tid >> 6;
  const int l15 = lane & 15, l16 = lane >> 4;
  const int q0 = blockIdx.x * 32, h = blockIdx.y, b = blockIdx.z;

  spk[tid] = speakers[b * T_ + tid];
  { int c = tid; int row = c >> 3, d0 = (c & 7) * 8;
    *(b16x8*)&Qs[row][d0] = *(const b16x8*)(q + (size_t)(b * T_ + q0 + row) * H_ + h * DH_ + d0); }

  const int wq = wid & 1, wk = wid >> 1;
  for (int kc = 0; kc < 4; ++kc) {
    __syncthreads();   // orders Q/spk staging (kc=0) and prior-iter Ks reads (kc>0)
#pragma unroll
    for (int j = 0; j < 2; ++j) {
      int c = tid + j * 256; int row = c >> 3, d0 = (c & 7) * 8;
      *(b16x8*)&Ks[row][d0] = *(const b16x8*)(kk_ + (size_t)(b * T_ + kc * 64 + row) * H_ + h * DH_ + d0);
    }
    __syncthreads();
    f32x4 sa[2] = {};
#pragma unroll
    for (int ks = 0; ks < 2; ++ks) {
      b16x8 af = *(const b16x8*)&Qs[wq * 16 + l15][ks * 32 + l16 * 8];
#pragma unroll
      for (int nn = 0; nn < 2; ++nn) {
        b16x8 bfr = *(const b16x8*)&Ks[wk * 32 + nn * 16 + l15][ks * 32 + l16 * 8];
        sa[nn] = __builtin_amdgcn_mfma_f32_16x16x32_bf16(af, bfr, sa[nn], 0, 0, 0);
      }
    }
#pragma unroll
    for (int nn = 0; nn < 2; ++nn)
#pragma unroll
      for (int rr = 0; rr < 4; ++rr) {
        int row = wq * 16 + l16 * 4 + rr;
        int col = kc * 64 + wk * 32 + nn * 16 + l15;
        Ss[row][col] = sa[nn][rr] * 0.125f;
      }
  }
  __syncthreads();

  // softmax with on-the-fly mask bias (literal -10000 add to match reference numerics)
  {
    const int r = tid >> 3, p = tid & 7, j = q0 + r;
    const int L = lengths[b];
    const int spj = spk[j];
    const bool rv = j < L;
    const int c0 = p * 32;
    float mx = -3.4e38f;
    for (int c = c0; c < c0 + 32; ++c) {
      bool ok;
      int dj = j - c;
      if (BR == 0)      ok = (c < L);
      else if (BR == 1) ok = rv && (c < L) && (dj <= 2) && (dj >= -2);
      else if (BR == 2) ok = rv && (spk[c] == spj);
      else              ok = rv && (spk[c] != spj) && (c < L);
      float s = Ss[r][c] + (ok ? 0.0f : -10000.0f);
      Ss[r][c] = s;
      mx = fmaxf(mx, s);
    }
    mx = fmaxf(mx, __shfl_xor(mx, 1));
    mx = fmaxf(mx, __shfl_xor(mx, 2));
    mx = fmaxf(mx, __shfl_xor(mx, 4));
    float sum = 0.f;
    for (int c = c0; c < c0 + 32; ++c) {
      float e = __expf(Ss[r][c] - mx);
      Ss[r][c] = e;
      sum += e;
    }
    sum += __shfl_xor(sum, 1); sum += __shfl_xor(sum, 2); sum += __shfl_xor(sum, 4);
    float inv = 1.f / sum;
    for (int c = c0; c < c0 + 32; ++c) Pb[r][c] = (__bf16)(Ss[r][c] * inv);
  }
  __syncthreads();

  // stage V^T into the (dead) Ss region
  __bf16* Vs = (__bf16*)&Ss[0][0];
#pragma unroll
  for (int j = 0; j < 8; ++j) {
    int c = tid + j * 256; int d = c >> 5, t0 = (c & 31) * 8;
    *(b16x8*)&Vs[d * 264 + t0] = *(const b16x8*)(vt + (size_t)(b * NH_ + h) * (DH_ * T_) + d * T_ + t0);
  }
  __syncthreads();

  // PV
  const int mh = wid & 1, nh = wid >> 1;
  f32x4 oa[2] = {};
#pragma unroll
  for (int kt = 0; kt < 8; ++kt) {
    b16x8 af = *(const b16x8*)&Pb[mh * 16 + l15][kt * 32 + l16 * 8];
#pragma unroll
    for (int n = 0; n < 2; ++n) {
      b16x8 bfr = *(const b16x8*)&Vs[(nh * 32 + n * 16 + l15) * 264 + kt * 32 + l16 * 8];
      oa[n] = __builtin_amdgcn_mfma_f32_16x16x32_bf16(af, bfr, oa[n], 0, 0, 0);
    }
  }
#pragma unroll
  for (int n = 0; n < 2; ++n)
#pragma unroll
    for (int rr = 0; rr < 4; ++rr) {
      int row = mh * 16 + l16 * 4 + rr;
      int d = nh * 32 + n * 16 + l15;
      ctx[(size_t)(b * T_ + q0 + row) * 2048 + h * DH_ + d] = (__bf16)(oa[n][rr]);
    }
}

// ============================================================================
extern "C" void kernel_launch(void* const* d_in, const int* in_sizes, int n_in,
                              void* d_out, int out_size, void* d_ws, size_t ws_size,
                              hipStream_t stream) {
  const float* x        = (const float*)d_in[0];
  const int*   lengths  = (const int*)d_in[1];
  const int*   speakers = (const int*)d_in[2];
  const float* emo      = (const float*)d_in[3];
  const float* t_Wq = (const float*)d_in[4];
  const float* t_bq = (const float*)d_in[5];
  const float* t_Wk = (const float*)d_in[6];
  const float* t_bk = (const float*)d_in[7];
  const float* t_Wv = (const float*)d_in[8];
  const float* t_bv = (const float*)d_in[9];
  const float* t_Wo = (const float*)d_in[10];
  const float* t_bo = (const float*)d_in[11];
  const float* t_ln_g = (const float*)d_in[12];
  const float* t_ln_b = (const float*)d_in[13];
  const float* b_Wq = (const float*)d_in[14];
  const float* b_bq = (const float*)d_in[15];
  const float* b_Wk = (const float*)d_in[16];
  const float* b_bk = (const float*)d_in[17];
  const float* b_Wv = (const float*)d_in[18];
  const float* b_bv = (const float*)d_in[19];
  const float* b_Wo = (const float*)d_in[20];
  const float* b_bo = (const float*)d_in[21];
  const float* W1   = (const float*)d_in[22];
  const float* b1   = (const float*)d_in[23];
  const float* ln2_g = (const float*)d_in[24];
  const float* ln2_b = (const float*)d_in[25];
  const float* W2   = (const float*)d_in[26];

  if (ws_size < 263745536) return;  // diagnostic: absmax stays exactly 2.406250 if ws too small

  char* ws = (char*)d_ws;
  const size_t SL = 512 * 512;  // elements per transposed 512x512 weight slot
  __bf16* wT    = (__bf16*)(ws);               // 23 slots (12,058,624 B)
  __bf16* xb    = (__bf16*)(ws + 12058624);
  __bf16* qsent = (__bf16*)(ws + 28835840);    // reused as h_t bf16
  __bf16* ctxs  = (__bf16*)(ws + 45613056);    // reused as h_e bf16
  float*  kemo  = (float*)(ws + 62390272);
  float*  vemo  = (float*)(ws + 62404608);
  float*  tmpf  = (float*)(ws + 62418944);
  float*  h_t   = (float*)(ws + 95973376);
  __bf16* qb    = (__bf16*)(ws + 129527808);
  __bf16* kb    = (__bf16*)(ws + 146305024);
  __bf16* vb    = (__bf16*)(ws + 163082240);
  __bf16* vtb   = (__bf16*)(ws + 179859456);
  __bf16* ctxa  = (__bf16*)(ws + 196636672);
  __bf16* cat   = (__bf16*)(ws + 129527808);   // reuse qb..vtb region
  __bf16* htb   = qsent;
  __bf16* heb   = ctxs;

  // 1. x -> bf16
  cvt_f32_bf16_k<<<dim3(8192), 256, 0, stream>>>(x, xb);
  // 2. weight transposes (fp32 -> bf16, Bt[n][k])
  transpose_cvt<<<dim3(16, 16, 1), 256, 0, stream>>>(t_Wq, wT + 0 * SL, 512, 512);
  transpose_cvt<<<dim3(16, 16, 1), 256, 0, stream>>>(t_Wo, wT + 1 * SL, 512, 512);
  transpose_cvt<<<dim3(16, 16, 4), 256, 0, stream>>>(b_Wq, wT + 2 * SL, 512, 512);
  transpose_cvt<<<dim3(16, 16, 4), 256, 0, stream>>>(b_Wk, wT + 6 * SL, 512, 512);
  transpose_cvt<<<dim3(16, 16, 4), 256, 0, stream>>>(b_Wv, wT + 10 * SL, 512, 512);
  transpose_cvt<<<dim3(16, 16, 4), 256, 0, stream>>>(b_Wo, wT + 14 * SL, 512, 512);
  transpose_cvt<<<dim3(16, 64, 1), 256, 0, stream>>>(W1, wT + 18 * SL, 2048, 512);
  transpose_cvt<<<dim3(16, 16, 1), 256, 0, stream>>>(W2, wT + 22 * SL, 512, 512);
  // 3. emotion K/V (fp32, tiny)
  emo_kv<<<dim3(7, 2), 512, 0, stream>>>(emo, t_Wk, t_bk, t_Wv, t_bv, kemo, vemo);
  // 4. q_sent = x @ t_Wq + t_bq   (bf16 out)
  gemm_bt<true, true><<<dim3(4, 128), 256, 0, stream>>>(xb, wT + 0 * SL, t_bq, qsent, 512, 512, 512, 512);
  // 5. sentiment attention
  sent_attn<<<dim3(16384), 64, 0, stream>>>(qsent, kemo, vemo, ctxs);
  // 6. tmpf = ctx_sent @ t_Wo + t_bo  (fp32)
  gemm_bt<false, true><<<dim3(4, 128), 256, 0, stream>>>(ctxs, wT + 1 * SL, t_bo, tmpf, 512, 512, 512, 512);
  // 7. h_t = LN(tmpf + x)  -> fp32 + bf16
  ln_fused<<<dim3(16384), 256, 0, stream>>>(tmpf, x, t_ln_g, t_ln_b, h_t, htb);
  // 8. four masked attention branches
  for (int i = 0; i < 4; ++i) {
    gemm_bt<true, true><<<dim3(4, 128), 256, 0, stream>>>(htb, wT + (2 + i) * SL, b_bq + i * 512, qb, 512, 512, 512, 512);
    gemm_bt<true, true><<<dim3(4, 128), 256, 0, stream>>>(htb, wT + (6 + i) * SL, b_bk + i * 512, kb, 512, 512, 512, 512);
    gemm_bt<true, true><<<dim3(4, 128), 256, 0, stream>>>(htb, wT + (10 + i) * SL, b_bv + i * 512, vb, 512, 512, 512, 512);
    transpose_v_k<<<dim3(64, 8), 256, 0, stream>>>(vb, vtb);
    dim3 ag(8, 8, 64);
    switch (i) {
      case 0: attn_branch<0><<<ag, 256, 0, stream>>>(qb, kb, vtb, ctxa + 0 * 512, lengths, speakers); break;
      case 1: attn_branch<1><<<ag, 256, 0, stream>>>(qb, kb, vtb, ctxa + 1 * 512, lengths, speakers); break;
      case 2: attn_branch<2><<<ag, 256, 0, stream>>>(qb, kb, vtb, ctxa + 2 * 512, lengths, speakers); break;
      case 3: attn_branch<3><<<ag, 256, 0, stream>>>(qb, kb, vtb, ctxa + 3 * 512, lengths, speakers); break;
    }
  }
  // 9. cat[:, i*512:(i+1)*512] = ctx_i @ b_Wo[i] + b_bo[i]  (bf16)
  for (int i = 0; i < 4; ++i)
    gemm_bt<true, true><<<dim3(4, 128), 256, 0, stream>>>(ctxa + i * 512, wT + (14 + i) * SL, b_bo + i * 512, cat + i * 512, 512, 512, 2048, 2048);
  // 10. tmpf = cat @ W1 + b1  (K=2048, fp32)
  gemm_bt<false, true><<<dim3(4, 128), 256, 0, stream>>>(cat, wT + 18 * SL, b1, tmpf, 512, 2048, 2048, 512);
  // 11. h_e = LN(tmpf + h_t)  (bf16 only)
  ln_fused<<<dim3(16384), 256, 0, stream>>>(tmpf, h_t, ln2_g, ln2_b, nullptr, heb);
  // 12. out = h_e @ W2  (fp32 to d_out)
  gemm_bt<false, false><<<dim3(4, 128), 256, 0, stream>>>(heb, wT + 22 * SL, nullptr, (float*)d_out, 512, 512, 512, 512);
}

// Round 2
// 925.852 us; speedup vs baseline: 1.1852x; 1.1852x over previous
//
#include <hip/hip_runtime.h>

#define B_  64
#define T_  256
#define H_  512
#define NH_ 8
#define DH_ 64
#define M_  16384
#define SL  262144  // 512*512 elements per weight slot

typedef float  f32x4 __attribute__((ext_vector_type(4)));
typedef __bf16 b16x8 __attribute__((ext_vector_type(8)));
typedef __bf16 b16x4 __attribute__((ext_vector_type(4)));

__device__ __forceinline__ void gload16(const void* g, void* l) {
  __builtin_amdgcn_global_load_lds((const __attribute__((address_space(1))) void*)g,
                                   (__attribute__((address_space(3))) void*)l, 16, 0, 0);
}

// ---------------- fp32 -> bf16 convert ----------------
__global__ __launch_bounds__(256) void cvt_f32_bf16_k(const float* __restrict__ in,
                                                      __bf16* __restrict__ out) {
  size_t i = ((size_t)blockIdx.x * 256 + threadIdx.x) * 4;
  f32x4 v = *(const f32x4*)(in + i);
  b16x4 o;
  o[0] = (__bf16)v[0]; o[1] = (__bf16)v[1]; o[2] = (__bf16)v[2]; o[3] = (__bf16)v[3];
  *(b16x4*)(out + i) = o;
}

// ---------------- weight transpose + convert: out[c][r] = in[r][c] ----------------
__global__ __launch_bounds__(256) void transpose_cvt(const float* __restrict__ in,
                                                     __bf16* __restrict__ out, int R, int C, int ozs) {
  __shared__ float tile[32][33];
  in  += (size_t)blockIdx.z * R * C;
  out += (size_t)blockIdx.z * ozs;
  int c0 = blockIdx.x * 32, r0 = blockIdx.y * 32;
  int tx = threadIdx.x & 31, ty = threadIdx.x >> 5;
  for (int yy = ty; yy < 32; yy += 8)
    tile[yy][tx] = in[(size_t)(r0 + yy) * C + c0 + tx];
  __syncthreads();
  for (int yy = ty; yy < 32; yy += 8)
    out[(size_t)(c0 + yy) * R + r0 + tx] = (__bf16)tile[tx][yy];
}

// ---------------- emotion K/V: (7,512) = emo @ W + b ----------------
__global__ __launch_bounds__(512) void emo_kv(const float* __restrict__ emo,
                                              const float* __restrict__ Wk, const float* __restrict__ bk,
                                              const float* __restrict__ Wv, const float* __restrict__ bv,
                                              float* __restrict__ kout, float* __restrict__ vout) {
  int e = blockIdx.x, n = threadIdx.x;
  const float* W = blockIdx.y ? Wv : Wk;
  const float* bb = blockIdx.y ? bv : bk;
  float* o = blockIdx.y ? vout : kout;
  float acc = 0.f;
  for (int kk = 0; kk < 512; ++kk) acc += emo[e * 512 + kk] * W[kk * 512 + n];
  o[e * 512 + n] = acc + bb[n];
}

// ---------------- bias helpers ----------------
__global__ __launch_bounds__(512) void concat_qkv_bias(const float* __restrict__ bq,
                                                       const float* __restrict__ bk,
                                                       const float* __restrict__ bv,
                                                       float* __restrict__ out) {
  int i = blockIdx.x, t = threadIdx.x;
  out[i * 1536 + t]        = bq[i * 512 + t];
  out[i * 1536 + 512 + t]  = bk[i * 512 + t];
  out[i * 1536 + 1024 + t] = bv[i * 512 + t];
}

// bias2[o] = b1[o] + sum_g bo_flat[g] * W1[g][o]
__global__ __launch_bounds__(256) void make_bias2(const float* __restrict__ b1,
                                                  const float* __restrict__ bo,
                                                  const float* __restrict__ W1,
                                                  float* __restrict__ out) {
  int o = blockIdx.x * 256 + threadIdx.x;
  float acc = b1[o];
  for (int g = 0; g < 2048; ++g) acc += bo[g] * W1[(size_t)g * 512 + o];
  out[o] = acc;
}

// ---------------- MFMA GEMM (m97 structure): C[M,N] = A[M,K] @ Bt[N,K]^T + bias ----------------
template<bool OB, bool HB>
__global__ __launch_bounds__(256) void gemm_bt(const __bf16* __restrict__ A,
                                               const __bf16* __restrict__ Bt,
                                               const float* __restrict__ bias,
                                               void* __restrict__ Cv,
                                               int N, int K, int lda, int ldc) {
  __shared__ __attribute__((aligned(16))) __bf16 As[128 * 32];
  __shared__ __attribute__((aligned(16))) __bf16 Bs[128 * 32];
  const int tid = threadIdx.x, lane = tid & 63, wid = tid >> 6;
  const int wm = wid & 1, wn = wid >> 1;
  const int m0 = blockIdx.y * 128, n0 = blockIdx.x * 128;
  const int l15 = lane & 15, l16 = lane >> 4;
  const int r0 = tid >> 2, o0 = (tid & 3) * 8;
  const __bf16* a0 = A + (size_t)(m0 + r0) * lda + o0;
  const __bf16* a1 = A + (size_t)(m0 + 64 + r0) * lda + o0;
  const __bf16* bp0 = Bt + (size_t)(n0 + r0) * K + o0;
  const __bf16* bp1 = Bt + (size_t)(n0 + 64 + r0) * K + o0;
  char* AsW = (char*)As + wid * 1024;
  char* BsW = (char*)Bs + wid * 1024;
  f32x4 acc[4][4] = {};
  for (int k0 = 0; k0 < K; k0 += 32) {
    gload16(a0 + k0, AsW);
    gload16(a1 + k0, AsW + 4096);
    gload16(bp0 + k0, BsW);
    gload16(bp1 + k0, BsW + 4096);
    __syncthreads();                      // drains vmcnt(0): tiles ready
    b16x8 af[4], bf[4];
#pragma unroll
    for (int m = 0; m < 4; ++m) af[m] = *(const b16x8*)&As[(wm * 64 + m * 16 + l15) * 32 + l16 * 8];
#pragma unroll
    for (int n = 0; n < 4; ++n) bf[n] = *(const b16x8*)&Bs[(wn * 64 + n * 16 + l15) * 32 + l16 * 8];
#pragma unroll
    for (int m = 0; m < 4; ++m)
#pragma unroll
      for (int n = 0; n < 4; ++n)
        acc[m][n] = __builtin_amdgcn_mfma_f32_16x16x32_bf16(af[m], bf[n], acc[m][n], 0, 0, 0);
    __syncthreads();                      // all frag reads done before next-iter staging
  }
  const int rbase = m0 + wm * 64 + l16 * 4;
  const int cb = n0 + wn * 64 + l15;
#pragma unroll
  for (int n = 0; n < 4; ++n) {
    int gc = cb + n * 16;
    float bv = HB ? bias[gc] : 0.0f;
#pragma unroll
    for (int m = 0; m < 4; ++m) {
#pragma unroll
      for (int rr = 0; rr < 4; ++rr) {
        int gr = rbase + m * 16 + rr;
        float val = acc[m][n][rr] + bv;
        if (OB) ((__bf16*)Cv)[(size_t)gr * ldc + gc] = (__bf16)val;
        else    ((float*)Cv)[(size_t)gr * ldc + gc] = val;
      }
    }
  }
}

// ---------------- sentiment attention: 7 emotion keys, 1 wave per token ----------------
__global__ __launch_bounds__(64) void sent_attn(const __bf16* __restrict__ qs,
                                                const float* __restrict__ kemo,
                                                const float* __restrict__ vemo,
                                                __bf16* __restrict__ out) {
  int m = blockIdx.x, lane = threadIdx.x;
  const __bf16* qrow = qs + (size_t)m * 512;
  for (int h = 0; h < 8; ++h) {
    float qd = (float)qrow[h * 64 + lane];
    float s[7];
#pragma unroll
    for (int e = 0; e < 7; ++e) {
      float pr = qd * kemo[e * 512 + h * 64 + lane];
#pragma unroll
      for (int off = 32; off; off >>= 1) pr += __shfl_xor(pr, off);
      s[e] = pr * 0.125f;
    }
    float mx = s[0];
#pragma unroll
    for (int e = 1; e < 7; ++e) mx = fmaxf(mx, s[e]);
    float p[7], sum = 0.f;
#pragma unroll
    for (int e = 0; e < 7; ++e) { p[e] = __expf(s[e] - mx); sum += p[e]; }
    float inv = 1.f / sum;
    float ctx = 0.f;
#pragma unroll
    for (int e = 0; e < 7; ++e) ctx += p[e] * vemo[e * 512 + h * 64 + lane];
    out[(size_t)m * 512 + h * 64 + lane] = (__bf16)(ctx * inv);
  }
}

// ---------------- fused bias-residual-LayerNorm over rows of 512 ----------------
__global__ __launch_bounds__(256) void ln_fused(const float* __restrict__ pre,
                                                const float* __restrict__ res,
                                                const float* __restrict__ g,
                                                const float* __restrict__ bt,
                                                float* __restrict__ of,
                                                __bf16* __restrict__ ob) {
  int row = blockIdx.x, t = threadIdx.x;
  size_t base = (size_t)row * 512;
  float v0 = pre[base + t] + res[base + t];
  float v1 = pre[base + 256 + t] + res[base + 256 + t];
  float s = v0 + v1, q = v0 * v0 + v1 * v1;
#pragma unroll
  for (int off = 32; off; off >>= 1) { s += __shfl_xor(s, off); q += __shfl_xor(q, off); }
  __shared__ float ls[4], lq[4];
  int wid = t >> 6, lane = t & 63;
  if (lane == 0) { ls[wid] = s; lq[wid] = q; }
  __syncthreads();
  s = ls[0] + ls[1] + ls[2] + ls[3];
  q = lq[0] + lq[1] + lq[2] + lq[3];
  float mean = s * (1.f / 512.f);
  float var = q * (1.f / 512.f) - mean * mean;
  float rstd = rsqrtf(fmaxf(var, 0.f) + 1e-12f);
  float o0 = (v0 - mean) * rstd * g[t] + bt[t];
  float o1 = (v1 - mean) * rstd * g[256 + t] + bt[256 + t];
  if (of) { of[base + t] = o0; of[base + 256 + t] = o1; }
  if (ob) { ob[base + t] = (__bf16)o0; ob[base + 256 + t] = (__bf16)o1; }
}

// ---------------- V transpose: vt[b][h][d][t] = v[(b,t)][h*64+d], input stride sv ----------------
__global__ __launch_bounds__(256) void transpose_v_k(const __bf16* __restrict__ v,
                                                     __bf16* __restrict__ vt, int sv) {
  __shared__ __attribute__((aligned(16))) __bf16 tile[256][72];
  int b = blockIdx.x, h = blockIdx.y;
#pragma unroll
  for (int j = 0; j < 8; ++j) {
    int c = threadIdx.x + j * 256; int t = c >> 3, d0 = (c & 7) * 8;
    *(b16x8*)&tile[t][d0] = *(const b16x8*)(v + (size_t)(b * T_ + t) * sv + h * DH_ + d0);
  }
  __syncthreads();
#pragma unroll
  for (int j = 0; j < 8; ++j) {
    int c = threadIdx.x + j * 256; int d = c >> 5, t0 = (c & 31) * 8;
    b16x8 o;
#pragma unroll
    for (int u = 0; u < 8; ++u) o[u] = tile[t0 + u][d];
    *(b16x8*)(vt + (size_t)(b * NH_ + h) * (DH_ * T_) + d * T_ + t0) = o;
  }
}

// ---------------- fused masked attention; grid (bh=512, qc=8) for XCD L2 reuse ----------------
template<int BR>
__global__ __launch_bounds__(256) void attn_branch(const __bf16* __restrict__ q,
                                                   const __bf16* __restrict__ kk_,
                                                   const __bf16* __restrict__ vt,
                                                   __bf16* __restrict__ ctx,
                                                   const int* __restrict__ lengths,
                                                   const int* __restrict__ speakers,
                                                   int sqk, int so) {
  __shared__ __attribute__((aligned(16))) __bf16 Qs[32 * 64];
  __shared__ __attribute__((aligned(16))) __bf16 Ks[64 * 64];
  __shared__ __attribute__((aligned(16))) float  Ss[32 * 260];
  __shared__ int   spk[256];
  __shared__ float rowinv[32];
  const int tid = threadIdx.x, lane = tid & 63, wid = tid >> 6;
  const int l15 = lane & 15, l16 = lane >> 4;
  const int bh = blockIdx.x, q0 = blockIdx.y * 32;
  const int b = bh >> 3, h = bh & 7;

  spk[tid] = speakers[b * T_ + tid];
  {  // stage Q 32x64 via global_load_lds, XOR-pre-swizzled source
    int row = tid >> 3, slot = tid & 7;
    gload16(q + (size_t)(b * T_ + q0 + row) * sqk + h * DH_ + ((slot ^ (row & 7)) * 8),
            (char*)Qs + wid * 1024);
  }
  const int wq = wid & 1, wk = wid >> 1;
  const int krow = tid >> 3, kslot = tid & 7;
  const size_t kbase = (size_t)(b * T_) * sqk + h * DH_;
  for (int kc = 0; kc < 4; ++kc) {
    __syncthreads();   // prior-chunk frag reads done before restaging Ks
    gload16(kk_ + kbase + (size_t)(kc * 64 + krow) * sqk + ((kslot ^ (krow & 7)) * 8),
            (char*)Ks + wid * 1024);
    gload16(kk_ + kbase + (size_t)(kc * 64 + 32 + krow) * sqk + ((kslot ^ (krow & 7)) * 8),
            (char*)Ks + 4096 + wid * 1024);
    __syncthreads();   // vmcnt(0) drain: Qs (first iter) + Ks ready
    f32x4 sa[2] = {};
#pragma unroll
    for (int ks = 0; ks < 2; ++ks) {
      int qrow = wq * 16 + l15;
      b16x8 af = *(const b16x8*)((char*)Qs + qrow * 128 + (((ks * 4 + l16) ^ (qrow & 7)) * 16));
#pragma unroll
      for (int nn = 0; nn < 2; ++nn) {
        int krw = wk * 32 + nn * 16 + l15;
        b16x8 bfr = *(const b16x8*)((char*)Ks + krw * 128 + (((ks * 4 + l16) ^ (krw & 7)) * 16));
        sa[nn] = __builtin_amdgcn_mfma_f32_16x16x32_bf16(af, bfr, sa[nn], 0, 0, 0);
      }
    }
#pragma unroll
    for (int nn = 0; nn < 2; ++nn)
#pragma unroll
      for (int rr = 0; rr < 4; ++rr)
        Ss[(wq * 16 + l16 * 4 + rr) * 260 + kc * 64 + wk * 32 + nn * 16 + l15] = sa[nn][rr] * 0.125f;
  }
  __syncthreads();

  // single-pass masked softmax: lane (r = tid>>3, p = tid&7) owns cols {p+8i}
  {
    const int r = tid >> 3, p = tid & 7, j = q0 + r;
    const int L = lengths[b];
    const int spj = spk[j];
    const bool rv = j < L;
    float ev[32];
    float mx = -3.4e38f;
#pragma unroll
    for (int i = 0; i < 32; ++i) {
      int c = p + i * 8;
      float s = Ss[r * 260 + c];
      int dj = j - c;
      bool ok;
      if (BR == 0)      ok = (c < L);
      else if (BR == 1) ok = rv && (c < L) && (dj <= 2) && (dj >= -2);
      else if (BR == 2) ok = rv && (spk[c] == spj);
      else              ok = rv && (spk[c] != spj) && (c < L);
      s += ok ? 0.0f : -10000.0f;
      ev[i] = s;
      mx = fmaxf(mx, s);
    }
    mx = fmaxf(mx, __shfl_xor(mx, 1));
    mx = fmaxf(mx, __shfl_xor(mx, 2));
    mx = fmaxf(mx, __shfl_xor(mx, 4));
    float sum = 0.f;
#pragma unroll
    for (int i = 0; i < 32; ++i) { float e = __expf(ev[i] - mx); ev[i] = e; sum += e; }
    sum += __shfl_xor(sum, 1); sum += __shfl_xor(sum, 2); sum += __shfl_xor(sum, 4);
    if (p == 0) rowinv[r] = 1.0f / sum;
    __syncthreads();           // all Ss reads complete before overwrite
    __bf16* PbW = (__bf16*)Ss; // P (unnormalized exp) overlays dead Ss region
#pragma unroll
    for (int i = 0; i < 32; ++i) PbW[r * 264 + p + i * 8] = (__bf16)ev[i];
  }
  __syncthreads();

  // PV: P from LDS, V^T direct from global (L2-resident; same-XCD reuse)
  const __bf16* Pb = (const __bf16*)Ss;
  const __bf16* vbase = vt + (size_t)bh * (DH_ * T_);
  const int mh = wid & 1, nh = wid >> 1;
  f32x4 oa[2] = {};
#pragma unroll
  for (int kt = 0; kt < 8; ++kt) {
    b16x8 af = *(const b16x8*)(Pb + (mh * 16 + l15) * 264 + kt * 32 + l16 * 8);
#pragma unroll
    for (int n = 0; n < 2; ++n) {
      int d = nh * 32 + n * 16 + l15;
      b16x8 bfr = *(const b16x8*)(vbase + d * T_ + kt * 32 + l16 * 8);
      oa[n] = __builtin_amdgcn_mfma_f32_16x16x32_bf16(af, bfr, oa[n], 0, 0, 0);
    }
  }
#pragma unroll
  for (int n = 0; n < 2; ++n)
#pragma unroll
    for (int rr = 0; rr < 4; ++rr) {
      int row = mh * 16 + l16 * 4 + rr;
      ctx[(size_t)(b * T_ + q0 + row) * so + h * DH_ + nh * 32 + n * 16 + l15]
          = (__bf16)(oa[n][rr] * rowinv[row]);
    }
}

// ============================================================================
extern "C" void kernel_launch(void* const* d_in, const int* in_sizes, int n_in,
                              void* d_out, int out_size, void* d_ws, size_t ws_size,
                              hipStream_t stream) {
  const float* x        = (const float*)d_in[0];
  const int*   lengths  = (const int*)d_in[1];
  const int*   speakers = (const int*)d_in[2];
  const float* emo      = (const float*)d_in[3];
  const float* t_Wq = (const float*)d_in[4];
  const float* t_bq = (const float*)d_in[5];
  const float* t_Wk = (const float*)d_in[6];
  const float* t_bk = (const float*)d_in[7];
  const float* t_Wv = (const float*)d_in[8];
  const float* t_bv = (const float*)d_in[9];
  const float* t_Wo = (const float*)d_in[10];
  const float* t_bo = (const float*)d_in[11];
  const float* t_ln_g = (const float*)d_in[12];
  const float* t_ln_b = (const float*)d_in[13];
  const float* b_Wq = (const float*)d_in[14];
  const float* b_bq = (const float*)d_in[15];
  const float* b_Wk = (const float*)d_in[16];
  const float* b_bk = (const float*)d_in[17];
  const float* b_Wv = (const float*)d_in[18];
  const float* b_bv = (const float*)d_in[19];
  const float* b_Wo = (const float*)d_in[20];
  const float* b_bo = (const float*)d_in[21];
  const float* W1   = (const float*)d_in[22];
  const float* b1   = (const float*)d_in[23];
  const float* ln2_g = (const float*)d_in[24];
  const float* ln2_b = (const float*)d_in[25];
  const float* W2   = (const float*)d_in[26];

  if (ws_size < 249092096) return;

  char* ws = (char*)d_ws;
  // slots: 0=t_WqT 1=t_WoT [2+3i,3+3i,4+3i]=Wq_i/Wk_i/Wv_i T  14..17=W1t  18=W2t
  __bf16* wT      = (__bf16*)(ws);
  __bf16* bWo_bf  = (__bf16*)(ws + 9961472);
  __bf16* Btbig   = (__bf16*)(ws + 12058624);
  float*  qkvbias = (float*)(ws + 14155776);
  float*  bias2   = (float*)(ws + 14180352);
  float*  kemo    = (float*)(ws + 14182400);
  float*  vemo    = (float*)(ws + 14196736);
  __bf16* xb      = (__bf16*)(ws + 14211072);   // reused: ctxs, heb
  __bf16* qsent   = (__bf16*)(ws + 30988288);   // reused: htb
  float*  tmpf    = (float*)(ws + 47765504);
  float*  h_t     = (float*)(ws + 81319936);
  __bf16* qkv     = (__bf16*)(ws + 114874368);  // [16384][1536], per-branch
  __bf16* vtb     = (__bf16*)(ws + 165206016);
  __bf16* ctxa    = (__bf16*)(ws + 181983232);  // [16384][2048]
  __bf16* ctxs = xb, *heb = xb, *htb = qsent;

  // conversions + transposes
  cvt_f32_bf16_k<<<dim3(8192), 256, 0, stream>>>(x, xb);
  cvt_f32_bf16_k<<<dim3(1024), 256, 0, stream>>>(b_Wo, bWo_bf);
  transpose_cvt<<<dim3(16, 16, 1), 256, 0, stream>>>(t_Wq, wT + 0 * SL, 512, 512, SL);
  transpose_cvt<<<dim3(16, 16, 1), 256, 0, stream>>>(t_Wo, wT + 1 * SL, 512, 512, SL);
  transpose_cvt<<<dim3(16, 16, 4), 256, 0, stream>>>(b_Wq, wT + 2 * SL, 512, 512, 3 * SL);
  transpose_cvt<<<dim3(16, 16, 4), 256, 0, stream>>>(b_Wk, wT + 3 * SL, 512, 512, 3 * SL);
  transpose_cvt<<<dim3(16, 16, 4), 256, 0, stream>>>(b_Wv, wT + 4 * SL, 512, 512, 3 * SL);
  transpose_cvt<<<dim3(16, 64, 1), 256, 0, stream>>>(W1, wT + 14 * SL, 2048, 512, 0);
  transpose_cvt<<<dim3(16, 16, 1), 256, 0, stream>>>(W2, wT + 18 * SL, 512, 512, 0);
  emo_kv<<<dim3(7, 2), 512, 0, stream>>>(emo, t_Wk, t_bk, t_Wv, t_bv, kemo, vemo);
  concat_qkv_bias<<<dim3(4), 512, 0, stream>>>(b_bq, b_bk, b_bv, qkvbias);
  make_bias2<<<dim3(2), 256, 0, stream>>>(b1, b_bo, W1, bias2);
  // Btbig[o][i*512+n] = (Wo_i . W1_i)^T : A = W1t slice (lda 2048), Bt = Wo_i (bf16, stride 512)
  for (int i = 0; i < 4; ++i)
    gemm_bt<true, false><<<dim3(4, 4), 256, 0, stream>>>(wT + 14 * SL + i * 512, bWo_bf + (size_t)i * SL,
                                                         nullptr, Btbig + i * 512, 512, 512, 2048, 2048);

  // sentiment attention block
  gemm_bt<true, true><<<dim3(4, 128), 256, 0, stream>>>(xb, wT + 0 * SL, t_bq, qsent, 512, 512, 512, 512);
  sent_attn<<<dim3(16384), 64, 0, stream>>>(qsent, kemo, vemo, ctxs);
  gemm_bt<false, true><<<dim3(4, 128), 256, 0, stream>>>(ctxs, wT + 1 * SL, t_bo, tmpf, 512, 512, 512, 512);
  ln_fused<<<dim3(16384), 256, 0, stream>>>(tmpf, x, t_ln_g, t_ln_b, h_t, htb);

  // four masked attention branches (qkv batched per branch: N=1536)
  for (int i = 0; i < 4; ++i) {
    gemm_bt<true, true><<<dim3(12, 128), 256, 0, stream>>>(htb, wT + (2 + 3 * i) * SL, qkvbias + i * 1536,
                                                           qkv, 1536, 512, 512, 1536);
    transpose_v_k<<<dim3(64, 8), 256, 0, stream>>>(qkv + 1024, vtb, 1536);
    dim3 ag(512, 8);
    switch (i) {
      case 0: attn_branch<0><<<ag, 256, 0, stream>>>(qkv, qkv + 512, vtb, ctxa + 0 * 512, lengths, speakers, 1536, 2048); break;
      case 1: attn_branch<1><<<ag, 256, 0, stream>>>(qkv, qkv + 512, vtb, ctxa + 1 * 512, lengths, speakers, 1536, 2048); break;
      case 2: attn_branch<2><<<ag, 256, 0, stream>>>(qkv, qkv + 512, vtb, ctxa + 2 * 512, lengths, speakers, 1536, 2048); break;
      case 3: attn_branch<3><<<ag, 256, 0, stream>>>(qkv, qkv + 512, vtb, ctxa + 3 * 512, lengths, speakers, 1536, 2048); break;
    }
  }

  // fused (cat @ blockdiag(Wo) @ W1): one K=2048 GEMM against precomputed Btbig
  gemm_bt<false, true><<<dim3(4, 128), 256, 0, stream>>>(ctxa, Btbig, bias2, tmpf, 512, 2048, 2048, 512);
  ln_fused<<<dim3(16384), 256, 0, stream>>>(tmpf, h_t, ln2_g, ln2_b, nullptr, heb);
  gemm_bt<false, false><<<dim3(4, 128), 256, 0, stream>>>(heb, wT + 18 * SL, nullptr, (float*)d_out, 512, 512, 512, 512);
}

// Round 3
// 821.390 us; speedup vs baseline: 1.3359x; 1.1272x over previous
//
#include <hip/hip_runtime.h>

#define B_  64
#define T_  256
#define H_  512
#define NH_ 8
#define DH_ 64
#define M_  16384
#define SL  262144  // 512*512 elements per weight slot

typedef float  f32x4 __attribute__((ext_vector_type(4)));
typedef __bf16 b16x8 __attribute__((ext_vector_type(8)));
typedef __bf16 b16x4 __attribute__((ext_vector_type(4)));

__device__ __forceinline__ void gload16(const void* g, void* l) {
  __builtin_amdgcn_global_load_lds((const __attribute__((address_space(1))) void*)g,
                                   (__attribute__((address_space(3))) void*)l, 16, 0, 0);
}

// ---------------- fp32 -> bf16 convert ----------------
__global__ __launch_bounds__(256) void cvt_f32_bf16_k(const float* __restrict__ in,
                                                      __bf16* __restrict__ out) {
  size_t i = ((size_t)blockIdx.x * 256 + threadIdx.x) * 4;
  f32x4 v = *(const f32x4*)(in + i);
  b16x4 o;
  o[0] = (__bf16)v[0]; o[1] = (__bf16)v[1]; o[2] = (__bf16)v[2]; o[3] = (__bf16)v[3];
  *(b16x4*)(out + i) = o;
}

// ---------------- weight transpose + convert: out[c][r] = in[r][c] ----------------
__global__ __launch_bounds__(256) void transpose_cvt(const float* __restrict__ in,
                                                     __bf16* __restrict__ out, int R, int C, int ozs) {
  __shared__ float tile[32][33];
  in  += (size_t)blockIdx.z * R * C;
  out += (size_t)blockIdx.z * ozs;
  int c0 = blockIdx.x * 32, r0 = blockIdx.y * 32;
  int tx = threadIdx.x & 31, ty = threadIdx.x >> 5;
  for (int yy = ty; yy < 32; yy += 8)
    tile[yy][tx] = in[(size_t)(r0 + yy) * C + c0 + tx];
  __syncthreads();
  for (int yy = ty; yy < 32; yy += 8)
    out[(size_t)(c0 + yy) * R + r0 + tx] = (__bf16)tile[tx][yy];
}

// ---------------- emotion K/V: (7,512) = emo @ W + b ----------------
__global__ __launch_bounds__(512) void emo_kv(const float* __restrict__ emo,
                                              const float* __restrict__ Wk, const float* __restrict__ bk,
                                              const float* __restrict__ Wv, const float* __restrict__ bv,
                                              float* __restrict__ kout, float* __restrict__ vout) {
  int e = blockIdx.x, n = threadIdx.x;
  const float* W = blockIdx.y ? Wv : Wk;
  const float* bb = blockIdx.y ? bv : bk;
  float* o = blockIdx.y ? vout : kout;
  float acc = 0.f;
  for (int kk = 0; kk < 512; ++kk) acc += emo[e * 512 + kk] * W[kk * 512 + n];
  o[e * 512 + n] = acc + bb[n];
}

// ---------------- bias helpers ----------------
__global__ __launch_bounds__(512) void concat_qk_bias(const float* __restrict__ bq,
                                                      const float* __restrict__ bk,
                                                      float* __restrict__ out) {
  int i = blockIdx.x, t = threadIdx.x;
  out[i * 1024 + t]       = bq[i * 512 + t];
  out[i * 1024 + 512 + t] = bk[i * 512 + t];
}

// bias2[o] = b1[o] + sum_g bo_flat[g] * W1[g][o]
__global__ __launch_bounds__(256) void make_bias2(const float* __restrict__ b1,
                                                  const float* __restrict__ bo,
                                                  const float* __restrict__ W1,
                                                  float* __restrict__ out) {
  int o = blockIdx.x * 256 + threadIdx.x;
  float acc = b1[o];
  for (int g = 0; g < 2048; ++g) acc += bo[g] * W1[(size_t)g * 512 + o];
  out[o] = acc;
}

// ---------------- MFMA GEMM (m97 structure + XCD swizzle): C = A @ Bt^T + bias ----------------
// BM: 0 = no bias, 1 = column bias (bias[gc]), 2 = row bias (bias[gr])
template<bool OB, int BM>
__global__ __launch_bounds__(256) void gemm_bt(const __bf16* __restrict__ A,
                                               const __bf16* __restrict__ Bt,
                                               const float* __restrict__ bias,
                                               void* __restrict__ Cv,
                                               int N, int K, int lda, int ldc,
                                               size_t zA, size_t zB, size_t zC) {
  __shared__ __attribute__((aligned(16))) __bf16 As[128 * 32];
  __shared__ __attribute__((aligned(16))) __bf16 Bs[128 * 32];
  A  += (size_t)blockIdx.z * zA;
  Bt += (size_t)blockIdx.z * zB;
  char* Cb = (char*)Cv + (size_t)blockIdx.z * zC * (OB ? 2 : 4);
  // bijective XCD swizzle: each XCD owns a contiguous chunk of row-panels
  const int gx = gridDim.x;
  const int nwg = gx * gridDim.y;
  const int bid = blockIdx.y * gx + blockIdx.x;
  const int cpx = nwg >> 3;
  const int swz = (bid & 7) * cpx + (bid >> 3);
  const int bx = swz % gx, by = swz / gx;
  const int tid = threadIdx.x, lane = tid & 63, wid = tid >> 6;
  const int wm = wid & 1, wn = wid >> 1;
  const int m0 = by * 128, n0 = bx * 128;
  const int l15 = lane & 15, l16 = lane >> 4;
  const int r0 = tid >> 2, o0 = (tid & 3) * 8;
  const __bf16* a0 = A + (size_t)(m0 + r0) * lda + o0;
  const __bf16* a1 = A + (size_t)(m0 + 64 + r0) * lda + o0;
  const __bf16* bp0 = Bt + (size_t)(n0 + r0) * K + o0;
  const __bf16* bp1 = Bt + (size_t)(n0 + 64 + r0) * K + o0;
  char* AsW = (char*)As + wid * 1024;
  char* BsW = (char*)Bs + wid * 1024;
  f32x4 acc[4][4] = {};
  for (int k0 = 0; k0 < K; k0 += 32) {
    gload16(a0 + k0, AsW);
    gload16(a1 + k0, AsW + 4096);
    gload16(bp0 + k0, BsW);
    gload16(bp1 + k0, BsW + 4096);
    __syncthreads();
    b16x8 af[4], bf[4];
#pragma unroll
    for (int m = 0; m < 4; ++m) af[m] = *(const b16x8*)&As[(wm * 64 + m * 16 + l15) * 32 + l16 * 8];
#pragma unroll
    for (int n = 0; n < 4; ++n) bf[n] = *(const b16x8*)&Bs[(wn * 64 + n * 16 + l15) * 32 + l16 * 8];
#pragma unroll
    for (int m = 0; m < 4; ++m)
#pragma unroll
      for (int n = 0; n < 4; ++n)
        acc[m][n] = __builtin_amdgcn_mfma_f32_16x16x32_bf16(af[m], bf[n], acc[m][n], 0, 0, 0);
    __syncthreads();
  }
  const int rbase = m0 + wm * 64 + l16 * 4;
  const int cb = n0 + wn * 64 + l15;
#pragma unroll
  for (int n = 0; n < 4; ++n) {
    int gc = cb + n * 16;
    float bc = (BM == 1) ? bias[gc] : 0.0f;
#pragma unroll
    for (int m = 0; m < 4; ++m) {
#pragma unroll
      for (int rr = 0; rr < 4; ++rr) {
        int gr = rbase + m * 16 + rr;
        float val = acc[m][n][rr] + ((BM == 2) ? bias[gr] : bc);
        if (OB) ((__bf16*)Cb)[(size_t)gr * ldc + gc] = (__bf16)val;
        else    ((float*)Cb)[(size_t)gr * ldc + gc] = val;
      }
    }
  }
}

// ---------------- sentiment attention: 7 emotion keys, 1 wave per token ----------------
__global__ __launch_bounds__(64) void sent_attn(const __bf16* __restrict__ qs,
                                                const float* __restrict__ kemo,
                                                const float* __restrict__ vemo,
                                                __bf16* __restrict__ out) {
  int m = blockIdx.x, lane = threadIdx.x;
  const __bf16* qrow = qs + (size_t)m * 512;
  for (int h = 0; h < 8; ++h) {
    float qd = (float)qrow[h * 64 + lane];
    float s[7];
#pragma unroll
    for (int e = 0; e < 7; ++e) {
      float pr = qd * kemo[e * 512 + h * 64 + lane];
#pragma unroll
      for (int off = 32; off; off >>= 1) pr += __shfl_xor(pr, off);
      s[e] = pr * 0.125f;
    }
    float mx = s[0];
#pragma unroll
    for (int e = 1; e < 7; ++e) mx = fmaxf(mx, s[e]);
    float p[7], sum = 0.f;
#pragma unroll
    for (int e = 0; e < 7; ++e) { p[e] = __expf(s[e] - mx); sum += p[e]; }
    float inv = 1.f / sum;
    float ctx = 0.f;
#pragma unroll
    for (int e = 0; e < 7; ++e) ctx += p[e] * vemo[e * 512 + h * 64 + lane];
    out[(size_t)m * 512 + h * 64 + lane] = (__bf16)(ctx * inv);
  }
}

// ---------------- fused bias-residual-LayerNorm over rows of 512 ----------------
__global__ __launch_bounds__(256) void ln_fused(const float* __restrict__ pre,
                                                const float* __restrict__ res,
                                                const float* __restrict__ g,
                                                const float* __restrict__ bt,
                                                float* __restrict__ of,
                                                __bf16* __restrict__ ob) {
  int row = blockIdx.x, t = threadIdx.x;
  size_t base = (size_t)row * 512;
  float v0 = pre[base + t] + res[base + t];
  float v1 = pre[base + 256 + t] + res[base + 256 + t];
  float s = v0 + v1, q = v0 * v0 + v1 * v1;
#pragma unroll
  for (int off = 32; off; off >>= 1) { s += __shfl_xor(s, off); q += __shfl_xor(q, off); }
  __shared__ float ls[4], lq[4];
  int wid = t >> 6, lane = t & 63;
  if (lane == 0) { ls[wid] = s; lq[wid] = q; }
  __syncthreads();
  s = ls[0] + ls[1] + ls[2] + ls[3];
  q = lq[0] + lq[1] + lq[2] + lq[3];
  float mean = s * (1.f / 512.f);
  float var = q * (1.f / 512.f) - mean * mean;
  float rstd = rsqrtf(fmaxf(var, 0.f) + 1e-12f);
  float o0 = (v0 - mean) * rstd * g[t] + bt[t];
  float o1 = (v1 - mean) * rstd * g[256 + t] + bt[256 + t];
  if (of) { of[base + t] = o0; of[base + 256 + t] = o1; }
  if (ob) { ob[base + t] = (__bf16)o0; ob[base + 256 + t] = (__bf16)o1; }
}

// ---------------- fused masked attention; all-K prefetch + in-register softmax ----------------
// grid (bh=512, qc=8); vt is [512][16384] for this branch (v-dim major)
template<int BR>
__global__ __launch_bounds__(256) void attn_branch(const __bf16* __restrict__ q,
                                                   const __bf16* __restrict__ kk_,
                                                   const __bf16* __restrict__ vt,
                                                   __bf16* __restrict__ ctx,
                                                   const int* __restrict__ lengths,
                                                   const int* __restrict__ speakers,
                                                   int sqk, int so) {
  __shared__ __attribute__((aligned(16))) __bf16 Ks[256 * 64];   // 32 KB, xor-swizzled slots
  __shared__ __attribute__((aligned(16))) __bf16 P[32 * 260];    // 16.25 KB
  __shared__ float redM[2][32];
  __shared__ float redS[2][32];
  __shared__ float rowinv[32];
  __shared__ int spk[256];
  const int tid = threadIdx.x, lane = tid & 63, wid = tid >> 6;
  const int l15 = lane & 15, l16 = lane >> 4;
  const int bh = blockIdx.x, q0 = blockIdx.y * 32;
  const int b = bh >> 3, h = bh & 7;
  const int wq = wid & 1, wk = wid >> 1;

  // prefetch ALL 256 K rows into LDS (linear dest, xor-pre-swizzled source slots)
  {
    const size_t kb0 = (size_t)(b * T_) * sqk + h * DH_;
    const int rsub = lane >> 3, slot = lane & 7;
#pragma unroll
    for (int j = 0; j < 8; ++j) {
      int row = (j * 4 + wid) * 8 + rsub;
      gload16(kk_ + kb0 + (size_t)row * sqk + ((slot ^ (row & 7)) * 8),
              (char*)Ks + (j * 4 + wid) * 1024);
    }
  }
  spk[tid] = speakers[b * T_ + tid];
  // Q fragments direct global -> regs (rows wq*16+l15)
  b16x8 af0, af1;
  {
    const __bf16* qr = q + (size_t)(b * T_ + q0 + wq * 16 + l15) * sqk + h * DH_;
    af0 = *(const b16x8*)(qr + l16 * 8);
    af1 = *(const b16x8*)(qr + 32 + l16 * 8);
  }
  __syncthreads();   // K gloads drained, spk visible

  // QK^T: all scores stay in registers. sa[kc][nn][rr]:
  //   row = wq*16 + l16*4 + rr ; col = kc*64 + wk*32 + nn*16 + l15
  f32x4 sa[4][2] = {};
#pragma unroll
  for (int kc = 0; kc < 4; ++kc) {
#pragma unroll
    for (int nn = 0; nn < 2; ++nn) {
      int krw = kc * 64 + wk * 32 + nn * 16 + l15;
      b16x8 b0 = *(const b16x8*)((char*)Ks + krw * 128 + ((l16 ^ (krw & 7)) * 16));
      sa[kc][nn] = __builtin_amdgcn_mfma_f32_16x16x32_bf16(af0, b0, sa[kc][nn], 0, 0, 0);
      b16x8 b1 = *(const b16x8*)((char*)Ks + krw * 128 + (((4 + l16) ^ (krw & 7)) * 16));
      sa[kc][nn] = __builtin_amdgcn_mfma_f32_16x16x32_bf16(af1, b1, sa[kc][nn], 0, 0, 0);
    }
  }

  // in-register masked softmax
  const int L = lengths[b];
  const int rloc = wq * 16 + l16 * 4;
  float ev[4][8];
  float mx[4];
#pragma unroll
  for (int rr = 0; rr < 4; ++rr) {
    const int j = q0 + rloc + rr;
    const int spj = spk[j];
    const bool rv = j < L;
    mx[rr] = -3.4e38f;
#pragma unroll
    for (int kc = 0; kc < 4; ++kc)
#pragma unroll
      for (int nn = 0; nn < 2; ++nn) {
        int c = kc * 64 + wk * 32 + nn * 16 + l15;
        int dj = j - c;
        bool ok;
        if (BR == 0)      ok = (c < L);
        else if (BR == 1) ok = rv && (c < L) && (dj <= 2) && (dj >= -2);
        else if (BR == 2) ok = rv && (spk[c] == spj);
        else              ok = rv && (spk[c] != spj) && (c < L);
        float s = sa[kc][nn][rr] * 0.125f + (ok ? 0.0f : -10000.0f);
        ev[rr][kc * 2 + nn] = s;
        mx[rr] = fmaxf(mx[rr], s);
      }
    mx[rr] = fmaxf(mx[rr], __shfl_xor(mx[rr], 1));
    mx[rr] = fmaxf(mx[rr], __shfl_xor(mx[rr], 2));
    mx[rr] = fmaxf(mx[rr], __shfl_xor(mx[rr], 4));
    mx[rr] = fmaxf(mx[rr], __shfl_xor(mx[rr], 8));
  }
  if (l15 == 0) {
#pragma unroll
    for (int rr = 0; rr < 4; ++rr) redM[wk][rloc + rr] = mx[rr];
  }
  __syncthreads();
  float sm[4];
#pragma unroll
  for (int rr = 0; rr < 4; ++rr) {
    float mxf = fmaxf(redM[0][rloc + rr], redM[1][rloc + rr]);
    float s = 0.f;
#pragma unroll
    for (int i = 0; i < 8; ++i) { float e = __expf(ev[rr][i] - mxf); ev[rr][i] = e; s += e; }
    s += __shfl_xor(s, 1); s += __shfl_xor(s, 2); s += __shfl_xor(s, 4); s += __shfl_xor(s, 8);
    sm[rr] = s;
  }
  if (l15 == 0) {
#pragma unroll
    for (int rr = 0; rr < 4; ++rr) redS[wk][rloc + rr] = sm[rr];
  }
  __syncthreads();
#pragma unroll
  for (int rr = 0; rr < 4; ++rr) {
    if (wk == 0 && l15 == 0)
      rowinv[rloc + rr] = 1.0f / (redS[0][rloc + rr] + redS[1][rloc + rr]);
#pragma unroll
    for (int kc = 0; kc < 4; ++kc)
#pragma unroll
      for (int nn = 0; nn < 2; ++nn)
        P[(rloc + rr) * 260 + kc * 64 + wk * 32 + nn * 16 + l15] = (__bf16)ev[rr][kc * 2 + nn];
  }
  __syncthreads();

  // PV: P (unnormalized) from LDS, V^T direct from global (L2-resident per XCD)
  const __bf16* vb2 = vt + (size_t)(h * DH_) * M_ + b * T_;
  const int mh = wid & 1, nh = wid >> 1;
  f32x4 oa[2] = {};
#pragma unroll
  for (int kt = 0; kt < 8; ++kt) {
    b16x8 afp = *(const b16x8*)(P + (mh * 16 + l15) * 260 + kt * 32 + l16 * 8);
#pragma unroll
    for (int n = 0; n < 2; ++n) {
      int d = nh * 32 + n * 16 + l15;
      b16x8 bfr = *(const b16x8*)(vb2 + (size_t)d * M_ + kt * 32 + l16 * 8);
      oa[n] = __builtin_amdgcn_mfma_f32_16x16x32_bf16(afp, bfr, oa[n], 0, 0, 0);
    }
  }
#pragma unroll
  for (int n = 0; n < 2; ++n)
#pragma unroll
    for (int rr = 0; rr < 4; ++rr) {
      int row = mh * 16 + l16 * 4 + rr;
      ctx[(size_t)(b * T_ + q0 + row) * so + h * DH_ + nh * 32 + n * 16 + l15]
          = (__bf16)(oa[n][rr] * rowinv[row]);
    }
}

// ============================================================================
extern "C" void kernel_launch(void* const* d_in, const int* in_sizes, int n_in,
                              void* d_out, int out_size, void* d_ws, size_t ws_size,
                              hipStream_t stream) {
  const float* x        = (const float*)d_in[0];
  const int*   lengths  = (const int*)d_in[1];
  const int*   speakers = (const int*)d_in[2];
  const float* emo      = (const float*)d_in[3];
  const float* t_Wq = (const float*)d_in[4];
  const float* t_bq = (const float*)d_in[5];
  const float* t_Wk = (const float*)d_in[6];
  const float* t_bk = (const float*)d_in[7];
  const float* t_Wv = (const float*)d_in[8];
  const float* t_bv = (const float*)d_in[9];
  const float* t_Wo = (const float*)d_in[10];
  const float* t_bo = (const float*)d_in[11];
  const float* t_ln_g = (const float*)d_in[12];
  const float* t_ln_b = (const float*)d_in[13];
  const float* b_Wq = (const float*)d_in[14];
  const float* b_bq = (const float*)d_in[15];
  const float* b_Wk = (const float*)d_in[16];
  const float* b_bk = (const float*)d_in[17];
  const float* b_Wv = (const float*)d_in[18];
  const float* b_bv = (const float*)d_in[19];
  const float* b_Wo = (const float*)d_in[20];
  const float* b_bo = (const float*)d_in[21];
  const float* W1   = (const float*)d_in[22];
  const float* b1   = (const float*)d_in[23];
  const float* ln2_g = (const float*)d_in[24];
  const float* ln2_b = (const float*)d_in[25];
  const float* W2   = (const float*)d_in[26];

  if (ws_size < 232314880) return;

  char* ws = (char*)d_ws;
  // wT slots: 0=t_WqT 1=t_WoT [2+2i,3+2i]=WqT_i/WkT_i  [10+i]=WvT_i  14..17=W1t  18=W2t
  __bf16* wT      = (__bf16*)(ws);
  __bf16* bWo_bf  = (__bf16*)(ws + 9961472);
  __bf16* Btbig   = (__bf16*)(ws + 12058624);
  float*  qkbias  = (float*)(ws + 14155776);
  float*  bias2   = (float*)(ws + 14172160);
  float*  kemo    = (float*)(ws + 14174208);
  float*  vemo    = (float*)(ws + 14188544);
  __bf16* xb      = (__bf16*)(ws + 14211072);   // reused: ctxs, heb
  __bf16* qsent   = (__bf16*)(ws + 30988288);   // reused: htb
  float*  tmpf    = (float*)(ws + 47765504);
  float*  h_t     = (float*)(ws + 81319936);
  __bf16* qkb     = (__bf16*)(ws + 114874368);  // [16384][1024] per branch
  __bf16* vtb     = (__bf16*)(ws + 148428800);  // [512][16384] per branch
  __bf16* ctxa    = (__bf16*)(ws + 165206016);  // [16384][2048]
  __bf16* ctxs = xb, *heb = xb, *htb = qsent;

  // conversions + transposes
  cvt_f32_bf16_k<<<dim3(8192), 256, 0, stream>>>(x, xb);
  cvt_f32_bf16_k<<<dim3(1024), 256, 0, stream>>>(b_Wo, bWo_bf);
  transpose_cvt<<<dim3(16, 16, 1), 256, 0, stream>>>(t_Wq, wT + 0 * SL, 512, 512, SL);
  transpose_cvt<<<dim3(16, 16, 1), 256, 0, stream>>>(t_Wo, wT + 1 * SL, 512, 512, SL);
  transpose_cvt<<<dim3(16, 16, 4), 256, 0, stream>>>(b_Wq, wT + 2 * SL, 512, 512, 2 * SL);
  transpose_cvt<<<dim3(16, 16, 4), 256, 0, stream>>>(b_Wk, wT + 3 * SL, 512, 512, 2 * SL);
  transpose_cvt<<<dim3(16, 16, 4), 256, 0, stream>>>(b_Wv, wT + 10 * SL, 512, 512, SL);
  transpose_cvt<<<dim3(16, 64, 1), 256, 0, stream>>>(W1, wT + 14 * SL, 2048, 512, 0);
  transpose_cvt<<<dim3(16, 16, 1), 256, 0, stream>>>(W2, wT + 18 * SL, 512, 512, 0);
  emo_kv<<<dim3(7, 2), 512, 0, stream>>>(emo, t_Wk, t_bk, t_Wv, t_bv, kemo, vemo);
  concat_qk_bias<<<dim3(4), 512, 0, stream>>>(b_bq, b_bk, qkbias);
  make_bias2<<<dim3(2), 256, 0, stream>>>(b1, b_bo, W1, bias2);
  // Btbig[o][i*512+n] = (Wo_i . W1_i)^T, batched over i via z
  gemm_bt<true, 0><<<dim3(4, 4, 4), 256, 0, stream>>>(wT + 14 * SL, bWo_bf, nullptr, Btbig,
                                                      512, 512, 2048, 2048, 512, SL, 512);

  // sentiment attention block
  gemm_bt<true, 1><<<dim3(4, 128), 256, 0, stream>>>(xb, wT + 0 * SL, t_bq, qsent, 512, 512, 512, 512, 0, 0, 0);
  sent_attn<<<dim3(16384), 64, 0, stream>>>(qsent, kemo, vemo, ctxs);
  gemm_bt<false, 1><<<dim3(4, 128), 256, 0, stream>>>(ctxs, wT + 1 * SL, t_bo, tmpf, 512, 512, 512, 512, 0, 0, 0);
  ln_fused<<<dim3(16384), 256, 0, stream>>>(tmpf, x, t_ln_g, t_ln_b, h_t, htb);

  // four masked attention branches
  for (int i = 0; i < 4; ++i) {
    // q,k projection: N=1024
    gemm_bt<true, 1><<<dim3(8, 128), 256, 0, stream>>>(htb, wT + (2 + 2 * i) * SL, qkbias + i * 1024,
                                                       qkb, 1024, 512, 512, 1024, 0, 0, 0);
    // V^T directly: C[d][token] = Wv^T . htb^T  (row bias = bv)
    gemm_bt<true, 2><<<dim3(128, 4), 256, 0, stream>>>(wT + (10 + i) * SL, htb, b_bv + i * 512,
                                                       vtb, 16384, 512, 512, 16384, 0, 0, 0);
    dim3 ag(512, 8);
    switch (i) {
      case 0: attn_branch<0><<<ag, 256, 0, stream>>>(qkb, qkb + 512, vtb, ctxa + 0 * 512, lengths, speakers, 1024, 2048); break;
      case 1: attn_branch<1><<<ag, 256, 0, stream>>>(qkb, qkb + 512, vtb, ctxa + 1 * 512, lengths, speakers, 1024, 2048); break;
      case 2: attn_branch<2><<<ag, 256, 0, stream>>>(qkb, qkb + 512, vtb, ctxa + 2 * 512, lengths, speakers, 1024, 2048); break;
      case 3: attn_branch<3><<<ag, 256, 0, stream>>>(qkb, qkb + 512, vtb, ctxa + 3 * 512, lengths, speakers, 1024, 2048); break;
    }
  }

  // fused (cat @ blockdiag(Wo) @ W1): one K=2048 GEMM
  gemm_bt<false, 1><<<dim3(4, 128), 256, 0, stream>>>(ctxa, Btbig, bias2, tmpf, 512, 2048, 2048, 512, 0, 0, 0);
  ln_fused<<<dim3(16384), 256, 0, stream>>>(tmpf, h_t, ln2_g, ln2_b, nullptr, heb);
  gemm_bt<false, 0><<<dim3(4, 128), 256, 0, stream>>>(heb, wT + 18 * SL, nullptr, (float*)d_out, 512, 512, 512, 512, 0, 0, 0);
}

// Round 4
// 731.999 us; speedup vs baseline: 1.4990x; 1.1221x over previous
//
#include <hip/hip_runtime.h>

#define B_  64
#define T_  256
#define H_  512
#define NH_ 8
#define DH_ 64
#define M_  16384
#define SL  262144  // 512*512 elements per weight slot

typedef float  f32x4 __attribute__((ext_vector_type(4)));
typedef __bf16 b16x8 __attribute__((ext_vector_type(8)));
typedef __bf16 b16x4 __attribute__((ext_vector_type(4)));

__device__ __forceinline__ void gload16(const void* g, void* l) {
  __builtin_amdgcn_global_load_lds((const __attribute__((address_space(1))) void*)g,
                                   (__attribute__((address_space(3))) void*)l, 16, 0, 0);
}

// ---------------- fp32 -> bf16 convert ----------------
__global__ __launch_bounds__(256) void cvt_f32_bf16_k(const float* __restrict__ in,
                                                      __bf16* __restrict__ out) {
  size_t i = ((size_t)blockIdx.x * 256 + threadIdx.x) * 4;
  f32x4 v = *(const f32x4*)(in + i);
  b16x4 o;
  o[0] = (__bf16)v[0]; o[1] = (__bf16)v[1]; o[2] = (__bf16)v[2]; o[3] = (__bf16)v[3];
  *(b16x4*)(out + i) = o;
}

// ---------------- batched weight transpose: 15 x (512x512) slices ----------------
struct TP15 { const float* src[15]; int slot[15]; };
__global__ __launch_bounds__(256) void transpose_cvt15(TP15 p, __bf16* __restrict__ wT) {
  __shared__ float tile[32][33];
  const float* in = p.src[blockIdx.z];
  __bf16* out = wT + (size_t)p.slot[blockIdx.z] * SL;
  int c0 = blockIdx.x * 32, r0 = blockIdx.y * 32;
  int tx = threadIdx.x & 31, ty = threadIdx.x >> 5;
  for (int yy = ty; yy < 32; yy += 8)
    tile[yy][tx] = in[(size_t)(r0 + yy) * 512 + c0 + tx];
  __syncthreads();
  for (int yy = ty; yy < 32; yy += 8)
    out[(size_t)(c0 + yy) * 512 + r0 + tx] = (__bf16)tile[tx][yy];
}

// ---------------- generic transpose + convert (for W1: 2048x512) ----------------
__global__ __launch_bounds__(256) void transpose_cvt(const float* __restrict__ in,
                                                     __bf16* __restrict__ out, int R, int C) {
  __shared__ float tile[32][33];
  int c0 = blockIdx.x * 32, r0 = blockIdx.y * 32;
  int tx = threadIdx.x & 31, ty = threadIdx.x >> 5;
  for (int yy = ty; yy < 32; yy += 8)
    tile[yy][tx] = in[(size_t)(r0 + yy) * C + c0 + tx];
  __syncthreads();
  for (int yy = ty; yy < 32; yy += 8)
    out[(size_t)(c0 + yy) * R + r0 + tx] = (__bf16)tile[tx][yy];
}

// ---------------- emotion K/V: (7,512) = emo @ W + b ----------------
__global__ __launch_bounds__(512) void emo_kv(const float* __restrict__ emo,
                                              const float* __restrict__ Wk, const float* __restrict__ bk,
                                              const float* __restrict__ Wv, const float* __restrict__ bv,
                                              float* __restrict__ kout, float* __restrict__ vout) {
  int e = blockIdx.x, n = threadIdx.x;
  const float* W = blockIdx.y ? Wv : Wk;
  const float* bb = blockIdx.y ? bv : bk;
  float* o = blockIdx.y ? vout : kout;
  float acc = 0.f;
  for (int kk = 0; kk < 512; ++kk) acc += emo[e * 512 + kk] * W[kk * 512 + n];
  o[e * 512 + n] = acc + bb[n];
}

// ---------------- bias helpers ----------------
__global__ __launch_bounds__(512) void concat_qk_bias(const float* __restrict__ bq,
                                                      const float* __restrict__ bk,
                                                      float* __restrict__ out) {
  int i = blockIdx.x, t = threadIdx.x;
  out[i * 1024 + t]       = bq[i * 512 + t];
  out[i * 1024 + 512 + t] = bk[i * 512 + t];
}

// bias2 stage 1: partial[p][o] = sum_{g in [128p,128p+128)} bo[g]*W1[g][o]
__global__ __launch_bounds__(256) void bias2_p1(const float* __restrict__ bo,
                                                const float* __restrict__ W1,
                                                float* __restrict__ partial) {
  int p = blockIdx.x, t = threadIdx.x;
  float a0 = 0.f, a1 = 0.f;
  for (int g = p * 128; g < p * 128 + 128; ++g) {
    float bg = bo[g];
    a0 += bg * W1[(size_t)g * 512 + t];
    a1 += bg * W1[(size_t)g * 512 + 256 + t];
  }
  partial[p * 512 + t] = a0;
  partial[p * 512 + 256 + t] = a1;
}

// bias2 stage 2: out[o] = b1[o] + sum_p partial[p][o]
__global__ __launch_bounds__(256) void bias2_p2(const float* __restrict__ b1,
                                                const float* __restrict__ partial,
                                                float* __restrict__ out) {
  int o = blockIdx.x * 256 + threadIdx.x;
  float acc = b1[o];
#pragma unroll
  for (int p = 0; p < 16; ++p) acc += partial[p * 512 + o];
  out[o] = acc;
}

// ---------------- MFMA GEMM 128x128 (m97 structure + XCD swizzle) ----------------
// BM: 0 = no bias, 1 = column bias (bias[gc]), 2 = row bias (bias[gr])
template<bool OB, int BM>
__global__ __launch_bounds__(256) void gemm_bt(const __bf16* __restrict__ A,
                                               const __bf16* __restrict__ Bt,
                                               const float* __restrict__ bias,
                                               void* __restrict__ Cv,
                                               int N, int K, int lda, int ldc,
                                               size_t zA, size_t zB, size_t zC) {
  __shared__ __attribute__((aligned(16))) __bf16 As[128 * 32];
  __shared__ __attribute__((aligned(16))) __bf16 Bs[128 * 32];
  A  += (size_t)blockIdx.z * zA;
  Bt += (size_t)blockIdx.z * zB;
  char* Cb = (char*)Cv + (size_t)blockIdx.z * zC * (OB ? 2 : 4);
  const int gx = gridDim.x;
  const int nwg = gx * gridDim.y;
  const int bid = blockIdx.y * gx + blockIdx.x;
  const int cpx = nwg >> 3;
  const int swz = (bid & 7) * cpx + (bid >> 3);
  const int bx = swz % gx, by = swz / gx;
  const int tid = threadIdx.x, lane = tid & 63, wid = tid >> 6;
  const int wm = wid & 1, wn = wid >> 1;
  const int m0 = by * 128, n0 = bx * 128;
  const int l15 = lane & 15, l16 = lane >> 4;
  const int r0 = tid >> 2, o0 = (tid & 3) * 8;
  const __bf16* a0 = A + (size_t)(m0 + r0) * lda + o0;
  const __bf16* a1 = A + (size_t)(m0 + 64 + r0) * lda + o0;
  const __bf16* bp0 = Bt + (size_t)(n0 + r0) * K + o0;
  const __bf16* bp1 = Bt + (size_t)(n0 + 64 + r0) * K + o0;
  char* AsW = (char*)As + wid * 1024;
  char* BsW = (char*)Bs + wid * 1024;
  f32x4 acc[4][4] = {};
  for (int k0 = 0; k0 < K; k0 += 32) {
    gload16(a0 + k0, AsW);
    gload16(a1 + k0, AsW + 4096);
    gload16(bp0 + k0, BsW);
    gload16(bp1 + k0, BsW + 4096);
    __syncthreads();
    b16x8 af[4], bf[4];
#pragma unroll
    for (int m = 0; m < 4; ++m) af[m] = *(const b16x8*)&As[(wm * 64 + m * 16 + l15) * 32 + l16 * 8];
#pragma unroll
    for (int n = 0; n < 4; ++n) bf[n] = *(const b16x8*)&Bs[(wn * 64 + n * 16 + l15) * 32 + l16 * 8];
#pragma unroll
    for (int m = 0; m < 4; ++m)
#pragma unroll
      for (int n = 0; n < 4; ++n)
        acc[m][n] = __builtin_amdgcn_mfma_f32_16x16x32_bf16(af[m], bf[n], acc[m][n], 0, 0, 0);
    __syncthreads();
  }
  const int rbase = m0 + wm * 64 + l16 * 4;
  const int cb = n0 + wn * 64 + l15;
#pragma unroll
  for (int n = 0; n < 4; ++n) {
    int gc = cb + n * 16;
    float bc = (BM == 1) ? bias[gc] : 0.0f;
#pragma unroll
    for (int m = 0; m < 4; ++m) {
#pragma unroll
      for (int rr = 0; rr < 4; ++rr) {
        int gr = rbase + m * 16 + rr;
        float val = acc[m][n][rr] + ((BM == 2) ? bias[gr] : bc);
        if (OB) ((__bf16*)Cb)[(size_t)gr * ldc + gc] = (__bf16)val;
        else    ((float*)Cb)[(size_t)gr * ldc + gc] = val;
      }
    }
  }
}

// ---------------- MFMA GEMM 128x64 (higher occupancy for skinny N) ----------------
template<bool OB, int BM>
__global__ __launch_bounds__(256) void gemm_bt64(const __bf16* __restrict__ A,
                                                 const __bf16* __restrict__ Bt,
                                                 const float* __restrict__ bias,
                                                 void* __restrict__ Cv,
                                                 int N, int K, int lda, int ldc,
                                                 size_t zA, size_t zB, size_t zC) {
  __shared__ __attribute__((aligned(16))) __bf16 As[128 * 32];
  __shared__ __attribute__((aligned(16))) __bf16 Bs[64 * 32];
  A  += (size_t)blockIdx.z * zA;
  Bt += (size_t)blockIdx.z * zB;
  char* Cb = (char*)Cv + (size_t)blockIdx.z * zC * (OB ? 2 : 4);
  const int gx = gridDim.x;
  const int nwg = gx * gridDim.y;
  const int bid = blockIdx.y * gx + blockIdx.x;
  const int cpx = nwg >> 3;
  const int swz = (bid & 7) * cpx + (bid >> 3);
  const int bx = swz % gx, by = swz / gx;
  const int tid = threadIdx.x, lane = tid & 63, wid = tid >> 6;
  const int m0 = by * 128, n0 = bx * 64;
  const int l15 = lane & 15, l16 = lane >> 4;
  const int r0 = tid >> 2, o0 = (tid & 3) * 8;
  const __bf16* a0 = A + (size_t)(m0 + r0) * lda + o0;
  const __bf16* a1 = A + (size_t)(m0 + 64 + r0) * lda + o0;
  const __bf16* bp0 = Bt + (size_t)(n0 + r0) * K + o0;   // 64 B rows
  char* AsW = (char*)As + wid * 1024;
  char* BsW = (char*)Bs + wid * 1024;
  f32x4 acc[2][4] = {};
  for (int k0 = 0; k0 < K; k0 += 32) {
    gload16(a0 + k0, AsW);
    gload16(a1 + k0, AsW + 4096);
    gload16(bp0 + k0, BsW);
    __syncthreads();
    b16x8 af[2], bf[4];
#pragma unroll
    for (int m = 0; m < 2; ++m) af[m] = *(const b16x8*)&As[(wid * 32 + m * 16 + l15) * 32 + l16 * 8];
#pragma unroll
    for (int n = 0; n < 4; ++n) bf[n] = *(const b16x8*)&Bs[(n * 16 + l15) * 32 + l16 * 8];
#pragma unroll
    for (int m = 0; m < 2; ++m)
#pragma unroll
      for (int n = 0; n < 4; ++n)
        acc[m][n] = __builtin_amdgcn_mfma_f32_16x16x32_bf16(af[m], bf[n], acc[m][n], 0, 0, 0);
    __syncthreads();
  }
  const int rbase = m0 + wid * 32 + l16 * 4;
  const int cb = n0 + l15;
#pragma unroll
  for (int n = 0; n < 4; ++n) {
    int gc = cb + n * 16;
    float bc = (BM == 1) ? bias[gc] : 0.0f;
#pragma unroll
    for (int m = 0; m < 2; ++m) {
#pragma unroll
      for (int rr = 0; rr < 4; ++rr) {
        int gr = rbase + m * 16 + rr;
        float val = acc[m][n][rr] + ((BM == 2) ? bias[gr] : bc);
        if (OB) ((__bf16*)Cb)[(size_t)gr * ldc + gc] = (__bf16)val;
        else    ((float*)Cb)[(size_t)gr * ldc + gc] = val;
      }
    }
  }
}

// ---------------- sentiment attention: 7 emotion keys, 4 tokens/block ----------------
__global__ __launch_bounds__(256) void sent_attn(const __bf16* __restrict__ qs,
                                                 const float* __restrict__ kemo,
                                                 const float* __restrict__ vemo,
                                                 __bf16* __restrict__ out) {
  int m = blockIdx.x * 4 + (threadIdx.x >> 6), lane = threadIdx.x & 63;
  const __bf16* qrow = qs + (size_t)m * 512;
  for (int h = 0; h < 8; ++h) {
    float qd = (float)qrow[h * 64 + lane];
    float s[7];
#pragma unroll
    for (int e = 0; e < 7; ++e) {
      float pr = qd * kemo[e * 512 + h * 64 + lane];
#pragma unroll
      for (int off = 32; off; off >>= 1) pr += __shfl_xor(pr, off);
      s[e] = pr * 0.125f;
    }
    float mx = s[0];
#pragma unroll
    for (int e = 1; e < 7; ++e) mx = fmaxf(mx, s[e]);
    float p[7], sum = 0.f;
#pragma unroll
    for (int e = 0; e < 7; ++e) { p[e] = __expf(s[e] - mx); sum += p[e]; }
    float inv = 1.f / sum;
    float ctx = 0.f;
#pragma unroll
    for (int e = 0; e < 7; ++e) ctx += p[e] * vemo[e * 512 + h * 64 + lane];
    out[(size_t)m * 512 + h * 64 + lane] = (__bf16)(ctx * inv);
  }
}

// ---------------- fused bias-residual-LayerNorm over rows of 512 ----------------
__global__ __launch_bounds__(256) void ln_fused(const float* __restrict__ pre,
                                                const float* __restrict__ res,
                                                const float* __restrict__ g,
                                                const float* __restrict__ bt,
                                                float* __restrict__ of,
                                                __bf16* __restrict__ ob) {
  int row = blockIdx.x, t = threadIdx.x;
  size_t base = (size_t)row * 512;
  float v0 = pre[base + t] + res[base + t];
  float v1 = pre[base + 256 + t] + res[base + 256 + t];
  float s = v0 + v1, q = v0 * v0 + v1 * v1;
#pragma unroll
  for (int off = 32; off; off >>= 1) { s += __shfl_xor(s, off); q += __shfl_xor(q, off); }
  __shared__ float ls[4], lq[4];
  int wid = t >> 6, lane = t & 63;
  if (lane == 0) { ls[wid] = s; lq[wid] = q; }
  __syncthreads();
  s = ls[0] + ls[1] + ls[2] + ls[3];
  q = lq[0] + lq[1] + lq[2] + lq[3];
  float mean = s * (1.f / 512.f);
  float var = q * (1.f / 512.f) - mean * mean;
  float rstd = rsqrtf(fmaxf(var, 0.f) + 1e-12f);
  float o0 = (v0 - mean) * rstd * g[t] + bt[t];
  float o1 = (v1 - mean) * rstd * g[256 + t] + bt[256 + t];
  if (of) { of[base + t] = o0; of[base + 256 + t] = o1; }
  if (ob) { ob[base + t] = (__bf16)o0; ob[base + 256 + t] = (__bf16)o1; }
}

// ---------------- fused masked attention; all-K prefetch + in-register softmax ----------------
// grid (bh=512, qc=8); vt is [512][16384] for this branch (v-dim major)
template<int BR>
__global__ __launch_bounds__(256) void attn_branch(const __bf16* __restrict__ q,
                                                   const __bf16* __restrict__ kk_,
                                                   const __bf16* __restrict__ vt,
                                                   __bf16* __restrict__ ctx,
                                                   const int* __restrict__ lengths,
                                                   const int* __restrict__ speakers,
                                                   int sqk, int so) {
  __shared__ __attribute__((aligned(16))) __bf16 Ks[256 * 64];   // 32 KB, xor-swizzled slots
  __shared__ __attribute__((aligned(16))) __bf16 P[32 * 260];    // 16.25 KB
  __shared__ float redM[2][32];
  __shared__ float redS[2][32];
  __shared__ float rowinv[32];
  __shared__ int spk[256];
  const int tid = threadIdx.x, lane = tid & 63, wid = tid >> 6;
  const int l15 = lane & 15, l16 = lane >> 4;
  const int bh = blockIdx.x, q0 = blockIdx.y * 32;
  const int b = bh >> 3, h = bh & 7;
  const int wq = wid & 1, wk = wid >> 1;

  // prefetch ALL 256 K rows into LDS (linear dest, xor-pre-swizzled source slots)
  {
    const size_t kb0 = (size_t)(b * T_) * sqk + h * DH_;
    const int rsub = lane >> 3, slot = lane & 7;
#pragma unroll
    for (int j = 0; j < 8; ++j) {
      int row = (j * 4 + wid) * 8 + rsub;
      gload16(kk_ + kb0 + (size_t)row * sqk + ((slot ^ (row & 7)) * 8),
              (char*)Ks + (j * 4 + wid) * 1024);
    }
  }
  spk[tid] = speakers[b * T_ + tid];
  // Q fragments direct global -> regs (rows wq*16+l15)
  b16x8 af0, af1;
  {
    const __bf16* qr = q + (size_t)(b * T_ + q0 + wq * 16 + l15) * sqk + h * DH_;
    af0 = *(const b16x8*)(qr + l16 * 8);
    af1 = *(const b16x8*)(qr + 32 + l16 * 8);
  }
  __syncthreads();   // K gloads drained, spk visible

  // QK^T: all scores stay in registers. sa[kc][nn][rr]:
  //   row = wq*16 + l16*4 + rr ; col = kc*64 + wk*32 + nn*16 + l15
  f32x4 sa[4][2] = {};
#pragma unroll
  for (int kc = 0; kc < 4; ++kc) {
#pragma unroll
    for (int nn = 0; nn < 2; ++nn) {
      int krw = kc * 64 + wk * 32 + nn * 16 + l15;
      b16x8 b0 = *(const b16x8*)((char*)Ks + krw * 128 + ((l16 ^ (krw & 7)) * 16));
      sa[kc][nn] = __builtin_amdgcn_mfma_f32_16x16x32_bf16(af0, b0, sa[kc][nn], 0, 0, 0);
      b16x8 b1 = *(const b16x8*)((char*)Ks + krw * 128 + (((4 + l16) ^ (krw & 7)) * 16));
      sa[kc][nn] = __builtin_amdgcn_mfma_f32_16x16x32_bf16(af1, b1, sa[kc][nn], 0, 0, 0);
    }
  }

  // in-register masked softmax
  const int L = lengths[b];
  const int rloc = wq * 16 + l16 * 4;
  float ev[4][8];
  float mx[4];
#pragma unroll
  for (int rr = 0; rr < 4; ++rr) {
    const int j = q0 + rloc + rr;
    const int spj = spk[j];
    const bool rv = j < L;
    mx[rr] = -3.4e38f;
#pragma unroll
    for (int kc = 0; kc < 4; ++kc)
#pragma unroll
      for (int nn = 0; nn < 2; ++nn) {
        int c = kc * 64 + wk * 32 + nn * 16 + l15;
        int dj = j - c;
        bool ok;
        if (BR == 0)      ok = (c < L);
        else if (BR == 1) ok = rv && (c < L) && (dj <= 2) && (dj >= -2);
        else if (BR == 2) ok = rv && (spk[c] == spj);
        else              ok = rv && (spk[c] != spj) && (c < L);
        float s = sa[kc][nn][rr] * 0.125f + (ok ? 0.0f : -10000.0f);
        ev[rr][kc * 2 + nn] = s;
        mx[rr] = fmaxf(mx[rr], s);
      }
    mx[rr] = fmaxf(mx[rr], __shfl_xor(mx[rr], 1));
    mx[rr] = fmaxf(mx[rr], __shfl_xor(mx[rr], 2));
    mx[rr] = fmaxf(mx[rr], __shfl_xor(mx[rr], 4));
    mx[rr] = fmaxf(mx[rr], __shfl_xor(mx[rr], 8));
  }
  if (l15 == 0) {
#pragma unroll
    for (int rr = 0; rr < 4; ++rr) redM[wk][rloc + rr] = mx[rr];
  }
  __syncthreads();
  float sm[4];
#pragma unroll
  for (int rr = 0; rr < 4; ++rr) {
    float mxf = fmaxf(redM[0][rloc + rr], redM[1][rloc + rr]);
    float s = 0.f;
#pragma unroll
    for (int i = 0; i < 8; ++i) { float e = __expf(ev[rr][i] - mxf); ev[rr][i] = e; s += e; }
    s += __shfl_xor(s, 1); s += __shfl_xor(s, 2); s += __shfl_xor(s, 4); s += __shfl_xor(s, 8);
    sm[rr] = s;
  }
  if (l15 == 0) {
#pragma unroll
    for (int rr = 0; rr < 4; ++rr) redS[wk][rloc + rr] = sm[rr];
  }
  __syncthreads();
#pragma unroll
  for (int rr = 0; rr < 4; ++rr) {
    if (wk == 0 && l15 == 0)
      rowinv[rloc + rr] = 1.0f / (redS[0][rloc + rr] + redS[1][rloc + rr]);
#pragma unroll
    for (int kc = 0; kc < 4; ++kc)
#pragma unroll
      for (int nn = 0; nn < 2; ++nn)
        P[(rloc + rr) * 260 + kc * 64 + wk * 32 + nn * 16 + l15] = (__bf16)ev[rr][kc * 2 + nn];
  }
  __syncthreads();

  // PV: P (unnormalized) from LDS, V^T direct from global (L2-resident per XCD)
  const __bf16* vb2 = vt + (size_t)(h * DH_) * M_ + b * T_;
  const int mh = wid & 1, nh = wid >> 1;
  f32x4 oa[2] = {};
#pragma unroll
  for (int kt = 0; kt < 8; ++kt) {
    b16x8 afp = *(const b16x8*)(P + (mh * 16 + l15) * 260 + kt * 32 + l16 * 8);
#pragma unroll
    for (int n = 0; n < 2; ++n) {
      int d = nh * 32 + n * 16 + l15;
      b16x8 bfr = *(const b16x8*)(vb2 + (size_t)d * M_ + kt * 32 + l16 * 8);
      oa[n] = __builtin_amdgcn_mfma_f32_16x16x32_bf16(afp, bfr, oa[n], 0, 0, 0);
    }
  }
#pragma unroll
  for (int n = 0; n < 2; ++n)
#pragma unroll
    for (int rr = 0; rr < 4; ++rr) {
      int row = mh * 16 + l16 * 4 + rr;
      ctx[(size_t)(b * T_ + q0 + row) * so + h * DH_ + nh * 32 + n * 16 + l15]
          = (__bf16)(oa[n][rr] * rowinv[row]);
    }
}

// ============================================================================
extern "C" void kernel_launch(void* const* d_in, const int* in_sizes, int n_in,
                              void* d_out, int out_size, void* d_ws, size_t ws_size,
                              hipStream_t stream) {
  const float* x        = (const float*)d_in[0];
  const int*   lengths  = (const int*)d_in[1];
  const int*   speakers = (const int*)d_in[2];
  const float* emo      = (const float*)d_in[3];
  const float* t_Wq = (const float*)d_in[4];
  const float* t_bq = (const float*)d_in[5];
  const float* t_Wk = (const float*)d_in[6];
  const float* t_bk = (const float*)d_in[7];
  const float* t_Wv = (const float*)d_in[8];
  const float* t_bv = (const float*)d_in[9];
  const float* t_Wo = (const float*)d_in[10];
  const float* t_bo = (const float*)d_in[11];
  const float* t_ln_g = (const float*)d_in[12];
  const float* t_ln_b = (const float*)d_in[13];
  const float* b_Wq = (const float*)d_in[14];
  const float* b_bq = (const float*)d_in[15];
  const float* b_Wk = (const float*)d_in[16];
  const float* b_bk = (const float*)d_in[17];
  const float* b_Wv = (const float*)d_in[18];
  const float* b_bv = (const float*)d_in[19];
  const float* b_Wo = (const float*)d_in[20];
  const float* b_bo = (const float*)d_in[21];
  const float* W1   = (const float*)d_in[22];
  const float* b1   = (const float*)d_in[23];
  const float* ln2_g = (const float*)d_in[24];
  const float* ln2_b = (const float*)d_in[25];
  const float* W2   = (const float*)d_in[26];

  if (ws_size < 232314880) return;

  char* ws = (char*)d_ws;
  // wT slots: 0=t_WqT 1=t_WoT [2+2i,3+2i]=WqT_i/WkT_i  [10+i]=WvT_i  14..17=W1t  18=W2t
  __bf16* wT      = (__bf16*)(ws);
  __bf16* bWo_bf  = (__bf16*)(ws + 9961472);
  __bf16* Btbig   = (__bf16*)(ws + 12058624);
  float*  qkbias  = (float*)(ws + 14155776);
  float*  bias2   = (float*)(ws + 14172160);
  float*  kemo    = (float*)(ws + 14174208);
  float*  vemo    = (float*)(ws + 14188544);
  __bf16* xb      = (__bf16*)(ws + 14211072);   // reused: ctxs, heb
  __bf16* qsent   = (__bf16*)(ws + 30988288);   // reused: htb
  float*  tmpf    = (float*)(ws + 47765504);
  float*  h_t     = (float*)(ws + 81319936);
  __bf16* qkb     = (__bf16*)(ws + 114874368);  // [16384][1024] per branch
  __bf16* vtb     = (__bf16*)(ws + 148428800);  // [512][16384] per branch
  __bf16* ctxa    = (__bf16*)(ws + 165206016);  // [16384][2048]
  __bf16* ctxs = xb, *heb = xb, *htb = qsent;
  float*  partial = tmpf;   // bias2 scratch; dead before tmpf's first real write

  // conversions + batched transposes
  cvt_f32_bf16_k<<<dim3(8192), 256, 0, stream>>>(x, xb);
  cvt_f32_bf16_k<<<dim3(1024), 256, 0, stream>>>(b_Wo, bWo_bf);
  {
    TP15 p;
    const float* srcs[15] = {t_Wq, t_Wo,
                             b_Wq, b_Wq + SL, b_Wq + 2 * SL, b_Wq + 3 * SL,
                             b_Wk, b_Wk + SL, b_Wk + 2 * SL, b_Wk + 3 * SL,
                             b_Wv, b_Wv + SL, b_Wv + 2 * SL, b_Wv + 3 * SL,
                             W2};
    const int slots[15] = {0, 1, 2, 4, 6, 8, 3, 5, 7, 9, 10, 11, 12, 13, 18};
    for (int i = 0; i < 15; ++i) { p.src[i] = srcs[i]; p.slot[i] = slots[i]; }
    transpose_cvt15<<<dim3(16, 16, 15), 256, 0, stream>>>(p, wT);
  }
  transpose_cvt<<<dim3(16, 64), 256, 0, stream>>>(W1, wT + 14 * SL, 2048, 512);
  emo_kv<<<dim3(7, 2), 512, 0, stream>>>(emo, t_Wk, t_bk, t_Wv, t_bv, kemo, vemo);
  concat_qk_bias<<<dim3(4), 512, 0, stream>>>(b_bq, b_bk, qkbias);
  bias2_p1<<<dim3(16), 256, 0, stream>>>(b_bo, W1, partial);
  bias2_p2<<<dim3(2), 256, 0, stream>>>(b1, partial, bias2);
  // Btbig[o][i*512+n] = (Wo_i . W1_i)^T, batched over i via z
  gemm_bt64<true, 0><<<dim3(8, 4, 4), 256, 0, stream>>>(wT + 14 * SL, bWo_bf, nullptr, Btbig,
                                                        512, 512, 2048, 2048, 512, SL, 512);

  // sentiment attention block
  gemm_bt64<true, 1><<<dim3(8, 128), 256, 0, stream>>>(xb, wT + 0 * SL, t_bq, qsent, 512, 512, 512, 512, 0, 0, 0);
  sent_attn<<<dim3(4096), 256, 0, stream>>>(qsent, kemo, vemo, ctxs);
  gemm_bt64<false, 1><<<dim3(8, 128), 256, 0, stream>>>(ctxs, wT + 1 * SL, t_bo, tmpf, 512, 512, 512, 512, 0, 0, 0);
  ln_fused<<<dim3(16384), 256, 0, stream>>>(tmpf, x, t_ln_g, t_ln_b, h_t, htb);

  // four masked attention branches
  for (int i = 0; i < 4; ++i) {
    // q,k projection: N=1024 (128x128 tile, grid 1024)
    gemm_bt<true, 1><<<dim3(8, 128), 256, 0, stream>>>(htb, wT + (2 + 2 * i) * SL, qkbias + i * 1024,
                                                       qkb, 1024, 512, 512, 1024, 0, 0, 0);
    // V^T directly: C[d][token] = Wv^T . htb^T  (row bias = bv); BN=64 -> grid 1024
    gemm_bt64<true, 2><<<dim3(256, 4), 256, 0, stream>>>(wT + (10 + i) * SL, htb, b_bv + i * 512,
                                                         vtb, 16384, 512, 512, 16384, 0, 0, 0);
    dim3 ag(512, 8);
    switch (i) {
      case 0: attn_branch<0><<<ag, 256, 0, stream>>>(qkb, qkb + 512, vtb, ctxa + 0 * 512, lengths, speakers, 1024, 2048); break;
      case 1: attn_branch<1><<<ag, 256, 0, stream>>>(qkb, qkb + 512, vtb, ctxa + 1 * 512, lengths, speakers, 1024, 2048); break;
      case 2: attn_branch<2><<<ag, 256, 0, stream>>>(qkb, qkb + 512, vtb, ctxa + 2 * 512, lengths, speakers, 1024, 2048); break;
      case 3: attn_branch<3><<<ag, 256, 0, stream>>>(qkb, qkb + 512, vtb, ctxa + 3 * 512, lengths, speakers, 1024, 2048); break;
    }
  }

  // fused (cat @ blockdiag(Wo) @ W1): one K=2048 GEMM, BN=64 -> grid 1024
  gemm_bt64<false, 1><<<dim3(8, 128), 256, 0, stream>>>(ctxa, Btbig, bias2, tmpf, 512, 2048, 2048, 512, 0, 0, 0);
  ln_fused<<<dim3(16384), 256, 0, stream>>>(tmpf, h_t, ln2_g, ln2_b, nullptr, heb);
  gemm_bt64<false, 0><<<dim3(8, 128), 256, 0, stream>>>(heb, wT + 18 * SL, nullptr, (float*)d_out, 512, 512, 512, 512, 0, 0, 0);
}

// Round 5
// 639.662 us; speedup vs baseline: 1.7154x; 1.1444x over previous
//
#include <hip/hip_runtime.h>

#define B_  64
#define T_  256
#define H_  512
#define NH_ 8
#define DH_ 64
#define M_  16384
#define SL  262144  // 512*512 elements per weight slot

typedef float  f32x4 __attribute__((ext_vector_type(4)));
typedef __bf16 b16x8 __attribute__((ext_vector_type(8)));
typedef __bf16 b16x4 __attribute__((ext_vector_type(4)));

__device__ __forceinline__ void gload16(const void* g, void* l) {
  __builtin_amdgcn_global_load_lds((const __attribute__((address_space(1))) void*)g,
                                   (__attribute__((address_space(3))) void*)l, 16, 0, 0);
}

// ---------------- fp32 -> bf16 convert ----------------
__global__ __launch_bounds__(256) void cvt_f32_bf16_k(const float* __restrict__ in,
                                                      __bf16* __restrict__ out) {
  size_t i = ((size_t)blockIdx.x * 256 + threadIdx.x) * 4;
  f32x4 v = *(const f32x4*)(in + i);
  b16x4 o;
  o[0] = (__bf16)v[0]; o[1] = (__bf16)v[1]; o[2] = (__bf16)v[2]; o[3] = (__bf16)v[3];
  *(b16x4*)(out + i) = o;
}

// ---------------- batched weight transpose: 15 x (512x512) slices ----------------
struct TP15 { const float* src[15]; int slot[15]; };
__global__ __launch_bounds__(256) void transpose_cvt15(TP15 p, __bf16* __restrict__ wT) {
  __shared__ float tile[32][33];
  const float* in = p.src[blockIdx.z];
  __bf16* out = wT + (size_t)p.slot[blockIdx.z] * SL;
  int c0 = blockIdx.x * 32, r0 = blockIdx.y * 32;
  int tx = threadIdx.x & 31, ty = threadIdx.x >> 5;
  for (int yy = ty; yy < 32; yy += 8)
    tile[yy][tx] = in[(size_t)(r0 + yy) * 512 + c0 + tx];
  __syncthreads();
  for (int yy = ty; yy < 32; yy += 8)
    out[(size_t)(c0 + yy) * 512 + r0 + tx] = (__bf16)tile[tx][yy];
}

// ---------------- generic transpose + convert (for W1: 2048x512) ----------------
__global__ __launch_bounds__(256) void transpose_cvt(const float* __restrict__ in,
                                                     __bf16* __restrict__ out, int R, int C) {
  __shared__ float tile[32][33];
  int c0 = blockIdx.x * 32, r0 = blockIdx.y * 32;
  int tx = threadIdx.x & 31, ty = threadIdx.x >> 5;
  for (int yy = ty; yy < 32; yy += 8)
    tile[yy][tx] = in[(size_t)(r0 + yy) * C + c0 + tx];
  __syncthreads();
  for (int yy = ty; yy < 32; yy += 8)
    out[(size_t)(c0 + yy) * R + r0 + tx] = (__bf16)tile[tx][yy];
}

// ---------------- emotion K/V: (7,512) = emo @ W + b ----------------
__global__ __launch_bounds__(512) void emo_kv(const float* __restrict__ emo,
                                              const float* __restrict__ Wk, const float* __restrict__ bk,
                                              const float* __restrict__ Wv, const float* __restrict__ bv,
                                              float* __restrict__ kout, float* __restrict__ vout) {
  int e = blockIdx.x, n = threadIdx.x;
  const float* W = blockIdx.y ? Wv : Wk;
  const float* bb = blockIdx.y ? bv : bk;
  float* o = blockIdx.y ? vout : kout;
  float acc = 0.f;
  for (int kk = 0; kk < 512; ++kk) acc += emo[e * 512 + kk] * W[kk * 512 + n];
  o[e * 512 + n] = acc + bb[n];
}

// ---------------- bias helpers ----------------
__global__ __launch_bounds__(512) void concat_qk_bias(const float* __restrict__ bq,
                                                      const float* __restrict__ bk,
                                                      float* __restrict__ out) {
  int i = blockIdx.x, t = threadIdx.x;
  out[i * 1024 + t]       = bq[i * 512 + t];
  out[i * 1024 + 512 + t] = bk[i * 512 + t];
}

// bias2 stage 1: partial[p][o] = sum_{g in [128p,128p+128)} bo[g]*W1[g][o]
__global__ __launch_bounds__(256) void bias2_p1(const float* __restrict__ bo,
                                                const float* __restrict__ W1,
                                                float* __restrict__ partial) {
  int p = blockIdx.x, t = threadIdx.x;
  float a0 = 0.f, a1 = 0.f;
  for (int g = p * 128; g < p * 128 + 128; ++g) {
    float bg = bo[g];
    a0 += bg * W1[(size_t)g * 512 + t];
    a1 += bg * W1[(size_t)g * 512 + 256 + t];
  }
  partial[p * 512 + t] = a0;
  partial[p * 512 + 256 + t] = a1;
}

// bias2 stage 2: out[o] = b1[o] + sum_p partial[p][o]
__global__ __launch_bounds__(256) void bias2_p2(const float* __restrict__ b1,
                                                const float* __restrict__ partial,
                                                float* __restrict__ out) {
  int o = blockIdx.x * 256 + threadIdx.x;
  float acc = b1[o];
#pragma unroll
  for (int p = 0; p < 16; ++p) acc += partial[p * 512 + o];
  out[o] = acc;
}

// ---------------- MFMA GEMM 128x128 (m97 structure + XCD swizzle) ----------------
// BM: 0 = no bias, 1 = column bias (bias[gc]), 2 = row bias (bias[gr])
template<bool OB, int BM>
__global__ __launch_bounds__(256) void gemm_bt(const __bf16* __restrict__ A,
                                               const __bf16* __restrict__ Bt,
                                               const float* __restrict__ bias,
                                               void* __restrict__ Cv,
                                               int N, int K, int lda, int ldc,
                                               size_t zA, size_t zB, size_t zC) {
  __shared__ __attribute__((aligned(16))) __bf16 As[128 * 32];
  __shared__ __attribute__((aligned(16))) __bf16 Bs[128 * 32];
  A  += (size_t)blockIdx.z * zA;
  Bt += (size_t)blockIdx.z * zB;
  char* Cb = (char*)Cv + (size_t)blockIdx.z * zC * (OB ? 2 : 4);
  const int gx = gridDim.x;
  const int nwg = gx * gridDim.y;
  const int bid = blockIdx.y * gx + blockIdx.x;
  const int cpx = nwg >> 3;
  const int swz = (bid & 7) * cpx + (bid >> 3);
  const int bx = swz % gx, by = swz / gx;
  const int tid = threadIdx.x, lane = tid & 63, wid = tid >> 6;
  const int wm = wid & 1, wn = wid >> 1;
  const int m0 = by * 128, n0 = bx * 128;
  const int l15 = lane & 15, l16 = lane >> 4;
  const int r0 = tid >> 2, o0 = (tid & 3) * 8;
  const __bf16* a0 = A + (size_t)(m0 + r0) * lda + o0;
  const __bf16* a1 = A + (size_t)(m0 + 64 + r0) * lda + o0;
  const __bf16* bp0 = Bt + (size_t)(n0 + r0) * K + o0;
  const __bf16* bp1 = Bt + (size_t)(n0 + 64 + r0) * K + o0;
  char* AsW = (char*)As + wid * 1024;
  char* BsW = (char*)Bs + wid * 1024;
  f32x4 acc[4][4] = {};
  for (int k0 = 0; k0 < K; k0 += 32) {
    gload16(a0 + k0, AsW);
    gload16(a1 + k0, AsW + 4096);
    gload16(bp0 + k0, BsW);
    gload16(bp1 + k0, BsW + 4096);
    __syncthreads();
    b16x8 af[4], bf[4];
#pragma unroll
    for (int m = 0; m < 4; ++m) af[m] = *(const b16x8*)&As[(wm * 64 + m * 16 + l15) * 32 + l16 * 8];
#pragma unroll
    for (int n = 0; n < 4; ++n) bf[n] = *(const b16x8*)&Bs[(wn * 64 + n * 16 + l15) * 32 + l16 * 8];
#pragma unroll
    for (int m = 0; m < 4; ++m)
#pragma unroll
      for (int n = 0; n < 4; ++n)
        acc[m][n] = __builtin_amdgcn_mfma_f32_16x16x32_bf16(af[m], bf[n], acc[m][n], 0, 0, 0);
    __syncthreads();
  }
  const int rbase = m0 + wm * 64 + l16 * 4;
  const int cb = n0 + wn * 64 + l15;
#pragma unroll
  for (int n = 0; n < 4; ++n) {
    int gc = cb + n * 16;
    float bc = (BM == 1) ? bias[gc] : 0.0f;
#pragma unroll
    for (int m = 0; m < 4; ++m) {
#pragma unroll
      for (int rr = 0; rr < 4; ++rr) {
        int gr = rbase + m * 16 + rr;
        float val = acc[m][n][rr] + ((BM == 2) ? bias[gr] : bc);
        if (OB) ((__bf16*)Cb)[(size_t)gr * ldc + gc] = (__bf16)val;
        else    ((float*)Cb)[(size_t)gr * ldc + gc] = val;
      }
    }
  }
}

// ---------------- MFMA GEMM 128x64 (higher occupancy for skinny N) ----------------
template<bool OB, int BM>
__global__ __launch_bounds__(256) void gemm_bt64(const __bf16* __restrict__ A,
                                                 const __bf16* __restrict__ Bt,
                                                 const float* __restrict__ bias,
                                                 void* __restrict__ Cv,
                                                 int N, int K, int lda, int ldc,
                                                 size_t zA, size_t zB, size_t zC) {
  __shared__ __attribute__((aligned(16))) __bf16 As[128 * 32];
  __shared__ __attribute__((aligned(16))) __bf16 Bs[64 * 32];
  A  += (size_t)blockIdx.z * zA;
  Bt += (size_t)blockIdx.z * zB;
  char* Cb = (char*)Cv + (size_t)blockIdx.z * zC * (OB ? 2 : 4);
  const int gx = gridDim.x;
  const int nwg = gx * gridDim.y;
  const int bid = blockIdx.y * gx + blockIdx.x;
  const int cpx = nwg >> 3;
  const int swz = (bid & 7) * cpx + (bid >> 3);
  const int bx = swz % gx, by = swz / gx;
  const int tid = threadIdx.x, lane = tid & 63, wid = tid >> 6;
  const int m0 = by * 128, n0 = bx * 64;
  const int l15 = lane & 15, l16 = lane >> 4;
  const int r0 = tid >> 2, o0 = (tid & 3) * 8;
  const __bf16* a0 = A + (size_t)(m0 + r0) * lda + o0;
  const __bf16* a1 = A + (size_t)(m0 + 64 + r0) * lda + o0;
  const __bf16* bp0 = Bt + (size_t)(n0 + r0) * K + o0;   // 64 B rows
  char* AsW = (char*)As + wid * 1024;
  char* BsW = (char*)Bs + wid * 1024;
  f32x4 acc[2][4] = {};
  for (int k0 = 0; k0 < K; k0 += 32) {
    gload16(a0 + k0, AsW);
    gload16(a1 + k0, AsW + 4096);
    gload16(bp0 + k0, BsW);
    __syncthreads();
    b16x8 af[2], bf[4];
#pragma unroll
    for (int m = 0; m < 2; ++m) af[m] = *(const b16x8*)&As[(wid * 32 + m * 16 + l15) * 32 + l16 * 8];
#pragma unroll
    for (int n = 0; n < 4; ++n) bf[n] = *(const b16x8*)&Bs[(n * 16 + l15) * 32 + l16 * 8];
#pragma unroll
    for (int m = 0; m < 2; ++m)
#pragma unroll
      for (int n = 0; n < 4; ++n)
        acc[m][n] = __builtin_amdgcn_mfma_f32_16x16x32_bf16(af[m], bf[n], acc[m][n], 0, 0, 0);
    __syncthreads();
  }
  const int rbase = m0 + wid * 32 + l16 * 4;
  const int cb = n0 + l15;
#pragma unroll
  for (int n = 0; n < 4; ++n) {
    int gc = cb + n * 16;
    float bc = (BM == 1) ? bias[gc] : 0.0f;
#pragma unroll
    for (int m = 0; m < 2; ++m) {
#pragma unroll
      for (int rr = 0; rr < 4; ++rr) {
        int gr = rbase + m * 16 + rr;
        float val = acc[m][n][rr] + ((BM == 2) ? bias[gr] : bc);
        if (OB) ((__bf16*)Cb)[(size_t)gr * ldc + gc] = (__bf16)val;
        else    ((float*)Cb)[(size_t)gr * ldc + gc] = val;
      }
    }
  }
}

// ---------------- sentiment attention: 8 lanes per token, dims in regs ----------------
// lane = (tok_sub<<3) | chunk ; wave handles 8 tokens; block (4 waves) = 32 tokens
__global__ __launch_bounds__(256) void sent_attn(const __bf16* __restrict__ qs,
                                                 const float* __restrict__ kemo,
                                                 const float* __restrict__ vemo,
                                                 __bf16* __restrict__ out) {
  const int lane = threadIdx.x & 63, wid = threadIdx.x >> 6;
  const int m = blockIdx.x * 32 + wid * 8 + (lane >> 3);
  const int ch = lane & 7;
  const size_t rowb = (size_t)m * 512;
#pragma unroll
  for (int h = 0; h < 8; ++h) {
    const int hb = h * 64 + ch * 8;
    b16x8 qv = *(const b16x8*)(qs + rowb + hb);
    float qf[8];
#pragma unroll
    for (int j = 0; j < 8; ++j) qf[j] = (float)qv[j];
    float s[7];
#pragma unroll
    for (int e = 0; e < 7; ++e) {
      const float* kp = kemo + e * 512 + hb;
      f32x4 k0 = *(const f32x4*)kp;
      f32x4 k1 = *(const f32x4*)(kp + 4);
      float pr = qf[0] * k0[0] + qf[1] * k0[1] + qf[2] * k0[2] + qf[3] * k0[3]
               + qf[4] * k1[0] + qf[5] * k1[1] + qf[6] * k1[2] + qf[7] * k1[3];
      pr += __shfl_xor(pr, 1);
      pr += __shfl_xor(pr, 2);
      pr += __shfl_xor(pr, 4);
      s[e] = pr * 0.125f;
    }
    float mx = s[0];
#pragma unroll
    for (int e = 1; e < 7; ++e) mx = fmaxf(mx, s[e]);
    float p[7], sum = 0.f;
#pragma unroll
    for (int e = 0; e < 7; ++e) { p[e] = __expf(s[e] - mx); sum += p[e]; }
    float inv = 1.f / sum;
    float c8[8] = {};
#pragma unroll
    for (int e = 0; e < 7; ++e) {
      const float* vp = vemo + e * 512 + hb;
      f32x4 v0 = *(const f32x4*)vp;
      f32x4 v1 = *(const f32x4*)(vp + 4);
      c8[0] += p[e] * v0[0]; c8[1] += p[e] * v0[1]; c8[2] += p[e] * v0[2]; c8[3] += p[e] * v0[3];
      c8[4] += p[e] * v1[0]; c8[5] += p[e] * v1[1]; c8[6] += p[e] * v1[2]; c8[7] += p[e] * v1[3];
    }
    b16x8 o;
#pragma unroll
    for (int j = 0; j < 8; ++j) o[j] = (__bf16)(c8[j] * inv);
    *(b16x8*)(out + rowb + hb) = o;
  }
}

// ---------------- fused bias-residual-LayerNorm over rows of 512 ----------------
__global__ __launch_bounds__(256) void ln_fused(const float* __restrict__ pre,
                                                const float* __restrict__ res,
                                                const float* __restrict__ g,
                                                const float* __restrict__ bt,
                                                float* __restrict__ of,
                                                __bf16* __restrict__ ob) {
  int row = blockIdx.x, t = threadIdx.x;
  size_t base = (size_t)row * 512;
  float v0 = pre[base + t] + res[base + t];
  float v1 = pre[base + 256 + t] + res[base + 256 + t];
  float s = v0 + v1, q = v0 * v0 + v1 * v1;
#pragma unroll
  for (int off = 32; off; off >>= 1) { s += __shfl_xor(s, off); q += __shfl_xor(q, off); }
  __shared__ float ls[4], lq[4];
  int wid = t >> 6, lane = t & 63;
  if (lane == 0) { ls[wid] = s; lq[wid] = q; }
  __syncthreads();
  s = ls[0] + ls[1] + ls[2] + ls[3];
  q = lq[0] + lq[1] + lq[2] + lq[3];
  float mean = s * (1.f / 512.f);
  float var = q * (1.f / 512.f) - mean * mean;
  float rstd = rsqrtf(fmaxf(var, 0.f) + 1e-12f);
  float o0 = (v0 - mean) * rstd * g[t] + bt[t];
  float o1 = (v1 - mean) * rstd * g[256 + t] + bt[256 + t];
  if (of) { of[base + t] = o0; of[base + 256 + t] = o1; }
  if (ob) { ob[base + t] = (__bf16)o0; ob[base + 256 + t] = (__bf16)o1; }
}

// ---------------- fused masked attention; P overlays Ks; V prefetch ----------------
// grid (bh=512, qc=8); vt is [512][16384] for this branch (v-dim major)
template<int BR>
__global__ __launch_bounds__(256, 4) void attn_branch(const __bf16* __restrict__ q,
                                                      const __bf16* __restrict__ kk_,
                                                      const __bf16* __restrict__ vt,
                                                      __bf16* __restrict__ ctx,
                                                      const int* __restrict__ lengths,
                                                      const int* __restrict__ speakers,
                                                      int sqk, int so) {
  __shared__ __attribute__((aligned(16))) __bf16 Ks[256 * 64];   // 32 KB; P overlays after QK^T
  __shared__ float redM[2][32];
  __shared__ float redS[2][32];
  __shared__ float rowinv[32];
  __shared__ int spk[256];
  const int tid = threadIdx.x, lane = tid & 63, wid = tid >> 6;
  const int l15 = lane & 15, l16 = lane >> 4;
  const int bh = blockIdx.x, q0 = blockIdx.y * 32;
  const int b = bh >> 3, h = bh & 7;
  const int wq = wid & 1, wk = wid >> 1;
  const int mh = wid & 1, nh = wid >> 1;
  const __bf16* vb2 = vt + (size_t)(h * DH_) * M_ + b * T_;

  // prefetch ALL 256 K rows into LDS (linear dest, xor-pre-swizzled source slots)
  {
    const size_t kb0 = (size_t)(b * T_) * sqk + h * DH_;
    const int rsub = lane >> 3, slot = lane & 7;
#pragma unroll
    for (int j = 0; j < 8; ++j) {
      int row = (j * 4 + wid) * 8 + rsub;
      gload16(kk_ + kb0 + (size_t)row * sqk + ((slot ^ (row & 7)) * 8),
              (char*)Ks + (j * 4 + wid) * 1024);
    }
  }
  spk[tid] = speakers[b * T_ + tid];
  // Q fragments direct global -> regs (rows wq*16+l15)
  b16x8 af0, af1;
  {
    const __bf16* qr = q + (size_t)(b * T_ + q0 + wq * 16 + l15) * sqk + h * DH_;
    af0 = *(const b16x8*)(qr + l16 * 8);
    af1 = *(const b16x8*)(qr + 32 + l16 * 8);
  }
  __syncthreads();   // K gloads drained, spk visible

  // QK^T: all scores stay in registers. sa[kc][nn][rr]:
  //   row = wq*16 + l16*4 + rr ; col = kc*64 + wk*32 + nn*16 + l15
  f32x4 sa[4][2] = {};
#pragma unroll
  for (int kc = 0; kc < 4; ++kc) {
#pragma unroll
    for (int nn = 0; nn < 2; ++nn) {
      int krw = kc * 64 + wk * 32 + nn * 16 + l15;
      b16x8 b0 = *(const b16x8*)((char*)Ks + krw * 128 + ((l16 ^ (krw & 7)) * 16));
      sa[kc][nn] = __builtin_amdgcn_mfma_f32_16x16x32_bf16(af0, b0, sa[kc][nn], 0, 0, 0);
      b16x8 b1 = *(const b16x8*)((char*)Ks + krw * 128 + (((4 + l16) ^ (krw & 7)) * 16));
      sa[kc][nn] = __builtin_amdgcn_mfma_f32_16x16x32_bf16(af1, b1, sa[kc][nn], 0, 0, 0);
    }
  }

  // prefetch first 2 kt-slices of V (issue-early; consumed in PV)
  b16x8 vpre[2][2];
#pragma unroll
  for (int kt = 0; kt < 2; ++kt)
#pragma unroll
    for (int n = 0; n < 2; ++n) {
      int d = nh * 32 + n * 16 + l15;
      vpre[kt][n] = *(const b16x8*)(vb2 + (size_t)d * M_ + kt * 32 + l16 * 8);
    }

  // in-register masked softmax
  const int L = lengths[b];
  const int rloc = wq * 16 + l16 * 4;
  float ev[4][8];
  float mx[4];
#pragma unroll
  for (int rr = 0; rr < 4; ++rr) {
    const int j = q0 + rloc + rr;
    const int spj = spk[j];
    const bool rv = j < L;
    mx[rr] = -3.4e38f;
#pragma unroll
    for (int kc = 0; kc < 4; ++kc)
#pragma unroll
      for (int nn = 0; nn < 2; ++nn) {
        int c = kc * 64 + wk * 32 + nn * 16 + l15;
        int dj = j - c;
        bool ok;
        if (BR == 0)      ok = (c < L);
        else if (BR == 1) ok = rv && (c < L) && (dj <= 2) && (dj >= -2);
        else if (BR == 2) ok = rv && (spk[c] == spj);
        else              ok = rv && (spk[c] != spj) && (c < L);
        float s = sa[kc][nn][rr] * 0.125f + (ok ? 0.0f : -10000.0f);
        ev[rr][kc * 2 + nn] = s;
        mx[rr] = fmaxf(mx[rr], s);
      }
    mx[rr] = fmaxf(mx[rr], __shfl_xor(mx[rr], 1));
    mx[rr] = fmaxf(mx[rr], __shfl_xor(mx[rr], 2));
    mx[rr] = fmaxf(mx[rr], __shfl_xor(mx[rr], 4));
    mx[rr] = fmaxf(mx[rr], __shfl_xor(mx[rr], 8));
  }
  if (l15 == 0) {
#pragma unroll
    for (int rr = 0; rr < 4; ++rr) redM[wk][rloc + rr] = mx[rr];
  }
  __syncthreads();   // also guarantees all Ks reads are complete
  float sm[4];
#pragma unroll
  for (int rr = 0; rr < 4; ++rr) {
    float mxf = fmaxf(redM[0][rloc + rr], redM[1][rloc + rr]);
    float s = 0.f;
#pragma unroll
    for (int i = 0; i < 8; ++i) { float e = __expf(ev[rr][i] - mxf); ev[rr][i] = e; s += e; }
    s += __shfl_xor(s, 1); s += __shfl_xor(s, 2); s += __shfl_xor(s, 4); s += __shfl_xor(s, 8);
    sm[rr] = s;
  }
  if (l15 == 0) {
#pragma unroll
    for (int rr = 0; rr < 4; ++rr) redS[wk][rloc + rr] = sm[rr];
  }
  __syncthreads();
  // P (unnormalized exp, bf16) overlays the dead Ks region
  __bf16* P = (__bf16*)Ks;
#pragma unroll
  for (int rr = 0; rr < 4; ++rr) {
    if (wk == 0 && l15 == 0)
      rowinv[rloc + rr] = 1.0f / (redS[0][rloc + rr] + redS[1][rloc + rr]);
#pragma unroll
    for (int kc = 0; kc < 4; ++kc)
#pragma unroll
      for (int nn = 0; nn < 2; ++nn)
        P[(rloc + rr) * 260 + kc * 64 + wk * 32 + nn * 16 + l15] = (__bf16)ev[rr][kc * 2 + nn];
  }
  __syncthreads();

  // PV: P from LDS, V^T from global (first 2 kt prefetched)
  f32x4 oa[2] = {};
#pragma unroll
  for (int kt = 0; kt < 8; ++kt) {
    b16x8 afp = *(const b16x8*)(P + (mh * 16 + l15) * 260 + kt * 32 + l16 * 8);
#pragma unroll
    for (int n = 0; n < 2; ++n) {
      b16x8 bfr;
      if (kt < 2) bfr = vpre[kt][n];
      else {
        int d = nh * 32 + n * 16 + l15;
        bfr = *(const b16x8*)(vb2 + (size_t)d * M_ + kt * 32 + l16 * 8);
      }
      oa[n] = __builtin_amdgcn_mfma_f32_16x16x32_bf16(afp, bfr, oa[n], 0, 0, 0);
    }
  }
#pragma unroll
  for (int n = 0; n < 2; ++n)
#pragma unroll
    for (int rr = 0; rr < 4; ++rr) {
      int row = mh * 16 + l16 * 4 + rr;
      ctx[(size_t)(b * T_ + q0 + row) * so + h * DH_ + nh * 32 + n * 16 + l15]
          = (__bf16)(oa[n][rr] * rowinv[row]);
    }
}

// ============================================================================
extern "C" void kernel_launch(void* const* d_in, const int* in_sizes, int n_in,
                              void* d_out, int out_size, void* d_ws, size_t ws_size,
                              hipStream_t stream) {
  const float* x        = (const float*)d_in[0];
  const int*   lengths  = (const int*)d_in[1];
  const int*   speakers = (const int*)d_in[2];
  const float* emo      = (const float*)d_in[3];
  const float* t_Wq = (const float*)d_in[4];
  const float* t_bq = (const float*)d_in[5];
  const float* t_Wk = (const float*)d_in[6];
  const float* t_bk = (const float*)d_in[7];
  const float* t_Wv = (const float*)d_in[8];
  const float* t_bv = (const float*)d_in[9];
  const float* t_Wo = (const float*)d_in[10];
  const float* t_bo = (const float*)d_in[11];
  const float* t_ln_g = (const float*)d_in[12];
  const float* t_ln_b = (const float*)d_in[13];
  const float* b_Wq = (const float*)d_in[14];
  const float* b_bq = (const float*)d_in[15];
  const float* b_Wk = (const float*)d_in[16];
  const float* b_bk = (const float*)d_in[17];
  const float* b_Wv = (const float*)d_in[18];
  const float* b_bv = (const float*)d_in[19];
  const float* b_Wo = (const float*)d_in[20];
  const float* b_bo = (const float*)d_in[21];
  const float* W1   = (const float*)d_in[22];
  const float* b1   = (const float*)d_in[23];
  const float* ln2_g = (const float*)d_in[24];
  const float* ln2_b = (const float*)d_in[25];
  const float* W2   = (const float*)d_in[26];

  if (ws_size < 232314880) return;

  char* ws = (char*)d_ws;
  // wT slots: 0=t_WqT 1=t_WoT [2+2i,3+2i]=WqT_i/WkT_i  [10+i]=WvT_i  14..17=W1t  18=W2t
  __bf16* wT      = (__bf16*)(ws);
  __bf16* bWo_bf  = (__bf16*)(ws + 9961472);
  __bf16* Btbig   = (__bf16*)(ws + 12058624);
  float*  qkbias  = (float*)(ws + 14155776);
  float*  bias2   = (float*)(ws + 14172160);
  float*  kemo    = (float*)(ws + 14174208);
  float*  vemo    = (float*)(ws + 14188544);
  __bf16* xb      = (__bf16*)(ws + 14211072);   // reused: ctxs, heb
  __bf16* qsent   = (__bf16*)(ws + 30988288);   // reused: htb
  float*  tmpf    = (float*)(ws + 47765504);
  float*  h_t     = (float*)(ws + 81319936);
  __bf16* qkb     = (__bf16*)(ws + 114874368);  // [16384][1024] per branch
  __bf16* vtb     = (__bf16*)(ws + 148428800);  // [512][16384] per branch
  __bf16* ctxa    = (__bf16*)(ws + 165206016);  // [16384][2048]
  __bf16* ctxs = xb, *heb = xb, *htb = qsent;
  float*  partial = tmpf;   // bias2 scratch; dead before tmpf's first real write

  // conversions + batched transposes
  cvt_f32_bf16_k<<<dim3(8192), 256, 0, stream>>>(x, xb);
  cvt_f32_bf16_k<<<dim3(1024), 256, 0, stream>>>(b_Wo, bWo_bf);
  {
    TP15 p;
    const float* srcs[15] = {t_Wq, t_Wo,
                             b_Wq, b_Wq + SL, b_Wq + 2 * SL, b_Wq + 3 * SL,
                             b_Wk, b_Wk + SL, b_Wk + 2 * SL, b_Wk + 3 * SL,
                             b_Wv, b_Wv + SL, b_Wv + 2 * SL, b_Wv + 3 * SL,
                             W2};
    const int slots[15] = {0, 1, 2, 4, 6, 8, 3, 5, 7, 9, 10, 11, 12, 13, 18};
    for (int i = 0; i < 15; ++i) { p.src[i] = srcs[i]; p.slot[i] = slots[i]; }
    transpose_cvt15<<<dim3(16, 16, 15), 256, 0, stream>>>(p, wT);
  }
  transpose_cvt<<<dim3(16, 64), 256, 0, stream>>>(W1, wT + 14 * SL, 2048, 512);
  emo_kv<<<dim3(7, 2), 512, 0, stream>>>(emo, t_Wk, t_bk, t_Wv, t_bv, kemo, vemo);
  concat_qk_bias<<<dim3(4), 512, 0, stream>>>(b_bq, b_bk, qkbias);
  bias2_p1<<<dim3(16), 256, 0, stream>>>(b_bo, W1, partial);
  bias2_p2<<<dim3(2), 256, 0, stream>>>(b1, partial, bias2);
  // Btbig[o][i*512+n] = (Wo_i . W1_i)^T, batched over i via z
  gemm_bt64<true, 0><<<dim3(8, 4, 4), 256, 0, stream>>>(wT + 14 * SL, bWo_bf, nullptr, Btbig,
                                                        512, 512, 2048, 2048, 512, SL, 512);

  // sentiment attention block
  gemm_bt64<true, 1><<<dim3(8, 128), 256, 0, stream>>>(xb, wT + 0 * SL, t_bq, qsent, 512, 512, 512, 512, 0, 0, 0);
  sent_attn<<<dim3(512), 256, 0, stream>>>(qsent, kemo, vemo, ctxs);
  gemm_bt64<false, 1><<<dim3(8, 128), 256, 0, stream>>>(ctxs, wT + 1 * SL, t_bo, tmpf, 512, 512, 512, 512, 0, 0, 0);
  ln_fused<<<dim3(16384), 256, 0, stream>>>(tmpf, x, t_ln_g, t_ln_b, h_t, htb);

  // four masked attention branches
  for (int i = 0; i < 4; ++i) {
    // q,k projection: N=1024 (128x128 tile, grid 1024)
    gemm_bt<true, 1><<<dim3(8, 128), 256, 0, stream>>>(htb, wT + (2 + 2 * i) * SL, qkbias + i * 1024,
                                                       qkb, 1024, 512, 512, 1024, 0, 0, 0);
    // V^T directly: C[d][token] = Wv^T . htb^T  (row bias = bv); BN=64 -> grid 1024
    gemm_bt64<true, 2><<<dim3(256, 4), 256, 0, stream>>>(wT + (10 + i) * SL, htb, b_bv + i * 512,
                                                         vtb, 16384, 512, 512, 16384, 0, 0, 0);
    dim3 ag(512, 8);
    switch (i) {
      case 0: attn_branch<0><<<ag, 256, 0, stream>>>(qkb, qkb + 512, vtb, ctxa + 0 * 512, lengths, speakers, 1024, 2048); break;
      case 1: attn_branch<1><<<ag, 256, 0, stream>>>(qkb, qkb + 512, vtb, ctxa + 1 * 512, lengths, speakers, 1024, 2048); break;
      case 2: attn_branch<2><<<ag, 256, 0, stream>>>(qkb, qkb + 512, vtb, ctxa + 2 * 512, lengths, speakers, 1024, 2048); break;
      case 3: attn_branch<3><<<ag, 256, 0, stream>>>(qkb, qkb + 512, vtb, ctxa + 3 * 512, lengths, speakers, 1024, 2048); break;
    }
  }

  // fused (cat @ blockdiag(Wo) @ W1): one K=2048 GEMM, BN=64 -> grid 1024
  gemm_bt64<false, 1><<<dim3(8, 128), 256, 0, stream>>>(ctxa, Btbig, bias2, tmpf, 512, 2048, 2048, 512, 0, 0, 0);
  ln_fused<<<dim3(16384), 256, 0, stream>>>(tmpf, h_t, ln2_g, ln2_b, nullptr, heb);
  gemm_bt64<false, 0><<<dim3(8, 128), 256, 0, stream>>>(heb, wT + 18 * SL, nullptr, (float*)d_out, 512, 512, 512, 512, 0, 0, 0);
}